// Round 3
// baseline (5043.553 us; speedup 1.0000x reference)
//
#include <hip/hip_runtime.h>
#include <hip/hip_bf16.h>

typedef __hip_bfloat16 bf16;

#define BM 64
#define BN 64
#define BK 16

__device__ __forceinline__ float bits2f(unsigned short u) {
    return __uint_as_float(((unsigned)u) << 16);
}

__device__ __forceinline__ void load4(const bf16* p, float* a) {
    ushort4 t = *(const ushort4*)p;
    a[0] = bits2f(t.x); a[1] = bits2f(t.y); a[2] = bits2f(t.z); a[3] = bits2f(t.w);
}
__device__ __forceinline__ void load4(const float* p, float* a) {
    float4 t = *(const float4*)p;
    a[0] = t.x; a[1] = t.y; a[2] = t.z; a[3] = t.w;
}

// C[M,N] = A[M,K] @ W[N,K]^T (+bias) (+res) (+oldC if ADDC) (relu if RELU)
// A row-stride lda, W row-stride ldw, C row-stride ldc; res row-stride == ldc.
template<typename TA, typename TC, int RELU, int ADDC>
__global__ __launch_bounds__(256)
void gemm_kernel(const TA* __restrict__ A, int lda,
                 const float* __restrict__ W, int ldw,
                 const float* __restrict__ bias,
                 const float* __restrict__ res,
                 TC* __restrict__ C, int ldc,
                 int M, int N, int K)
{
    __shared__ float As[BK][BM + 4];
    __shared__ float Ws[BK][BN + 4];
    const int tid = threadIdx.x;
    const int ty = tid >> 4;   // m sub-tile 0..15
    const int tx = tid & 15;   // n sub-tile 0..15
    const int m0 = blockIdx.y * BM;
    const int n0 = blockIdx.x * BN;

    const int lmm = tid >> 2;        // 0..63 row within tile
    const int lkk = (tid & 3) * 4;   // 0,4,8,12

    float acc[4][4] = {};

    for (int k0 = 0; k0 < K; k0 += BK) {
        float a[4], w[4];
        load4(A + (size_t)(m0 + lmm) * lda + k0 + lkk, a);
        load4(W + (size_t)(n0 + lmm) * ldw + k0 + lkk, w);
        __syncthreads();
        #pragma unroll
        for (int u = 0; u < 4; ++u) {
            As[lkk + u][lmm] = a[u];
            Ws[lkk + u][lmm] = w[u];
        }
        __syncthreads();
        #pragma unroll
        for (int kk = 0; kk < BK; ++kk) {
            float4 av = *(const float4*)&As[kk][ty * 4];
            float4 bv = *(const float4*)&Ws[kk][tx * 4];
            float am[4] = {av.x, av.y, av.z, av.w};
            float bn[4] = {bv.x, bv.y, bv.z, bv.w};
            #pragma unroll
            for (int i = 0; i < 4; ++i)
                #pragma unroll
                for (int j = 0; j < 4; ++j)
                    acc[i][j] += am[i] * bn[j];
        }
    }

    #pragma unroll
    for (int i = 0; i < 4; ++i) {
        int m = m0 + ty * 4 + i;
        #pragma unroll
        for (int j = 0; j < 4; ++j) {
            int n = n0 + tx * 4 + j;
            float c = acc[i][j];
            if (bias) c += bias[n];
            if (res)  c += res[(size_t)m * ldc + n];
            if (RELU) c = fmaxf(c, 0.f);
            if (ADDC) c += (float)C[(size_t)m * ldc + n];
            if (sizeof(TC) == 2) ((bf16*)C)[(size_t)m * ldc + n] = __float2bfloat16(c);
            else                 ((float*)C)[(size_t)m * ldc + n] = c;
        }
    }
}

// one block per (b', i) query row; T5 bucket computed inline.
__global__ __launch_bounds__(256)
void attn_kernel(const float* __restrict__ q, const float* __restrict__ k,
                 const float* __restrict__ v, const float* __restrict__ rel_emb,
                 const int* __restrict__ pmask, float* __restrict__ att)
{
    const int i  = blockIdx.x;   // 0..1023 row in raw-reshaped (B*H, L) view
    const int bp = blockIdx.y;   // 0..63
    const int h  = bp & 15;
    const int bb = bp >> 4;
    const int tid = threadIdx.x;

    __shared__ float qs[64];
    __shared__ float relh[32];
    __shared__ float pbuf[1024];
    __shared__ float red[4][64];
    __shared__ float sred[8];

    const size_t base = (size_t)bp * 65536;
    if (tid < 64) qs[tid] = q[base + (size_t)i * 64 + tid];
    if (tid < 32) relh[tid] = rel_emb[tid * 16 + h];
    __syncthreads();

    float s[4];
    float lmax = -1e30f;
    #pragma unroll
    for (int c = 0; c < 4; ++c) {
        int j = c * 256 + tid;
        const float* kr = k + base + (size_t)j * 64;
        float dot = 0.f;
        #pragma unroll
        for (int d = 0; d < 64; d += 4) {
            float4 kv = *(const float4*)&kr[d];
            dot += qs[d] * kv.x + qs[d+1] * kv.y + qs[d+2] * kv.z + qs[d+3] * kv.w;
        }
        // T5 relative bucket, bidirectional, num_buckets=32, max_distance=128
        int n = j - i, ret = 0;
        if (n < 0) { ret = 16; n = -n; }
        int b;
        if (n < 8) b = n;
        else {
            int vi = 8 + (int)(log2f((float)n * 0.125f) * 2.0f);
            b = vi < 15 ? vi : 15;
        }
        float pmv = (float)pmask[bb * 1024 + j];
        dot += relh[ret + b] + logf(pmv);
        s[c] = dot;
        lmax = fmaxf(lmax, dot);
    }

    const int lane = tid & 63, wid = tid >> 6;
    #pragma unroll
    for (int off = 32; off; off >>= 1) lmax = fmaxf(lmax, __shfl_down(lmax, off));
    if (lane == 0) sred[wid] = lmax;
    __syncthreads();
    if (tid == 0) sred[4] = fmaxf(fmaxf(sred[0], sred[1]), fmaxf(sred[2], sred[3]));
    __syncthreads();
    const float m = sred[4];

    float lsum = 0.f;
    #pragma unroll
    for (int c = 0; c < 4; ++c) {
        float e = expf(s[c] - m);
        pbuf[c * 256 + tid] = e;
        lsum += e;
    }
    #pragma unroll
    for (int off = 32; off; off >>= 1) lsum += __shfl_down(lsum, off);
    __syncthreads();   // pbuf fully written; sred[0..3] maxes consumed
    if (lane == 0) sred[wid] = lsum;
    __syncthreads();
    if (tid == 0) sred[5] = sred[0] + sred[1] + sred[2] + sred[3];
    __syncthreads();
    const float inv = 1.f / sred[5];

    // PV: wave c2 handles a j-range, lane d handles channel d (coalesced V reads)
    const int c2 = tid >> 6;
    const int d  = tid & 63;
    const float* vb = v + base;
    float partial = 0.f;
    for (int jj = 0; jj < 256; ++jj) {
        int j = c2 * 256 + jj;
        partial += pbuf[j] * vb[(size_t)j * 64 + d];
    }
    red[c2][d] = partial;
    __syncthreads();
    if (tid < 64) {
        float o = (red[0][tid] + red[1][tid] + red[2][tid] + red[3][tid]) * inv;
        att[base + (size_t)i * 64 + tid] = o;
    }
}

// epsilon-free layernorm over rows of 1024; fp32 in, fp32 out
__global__ __launch_bounds__(256)
void ln_kernel(const float* __restrict__ in, float* __restrict__ out)
{
    __shared__ float sred[8];
    const int row = blockIdx.x;
    const int tid = threadIdx.x;
    const float* rp = in + (size_t)row * 1024;
    float4 val = *(const float4*)&rp[tid * 4];

    float lsum = val.x + val.y + val.z + val.w;
    #pragma unroll
    for (int off = 32; off; off >>= 1) lsum += __shfl_down(lsum, off);
    const int lane = tid & 63, wid = tid >> 6;
    if (lane == 0) sred[wid] = lsum;
    __syncthreads();
    if (tid == 0) sred[4] = (sred[0] + sred[1] + sred[2] + sred[3]) * (1.f / 1024.f);
    __syncthreads();
    const float mean = sred[4];

    float dx = val.x - mean, dy = val.y - mean, dz = val.z - mean, dw = val.w - mean;
    float lsq = dx * dx + dy * dy + dz * dz + dw * dw;
    #pragma unroll
    for (int off = 32; off; off >>= 1) lsq += __shfl_down(lsq, off);
    __syncthreads();
    if (lane == 0) sred[wid] = lsq;
    __syncthreads();
    if (tid == 0) sred[5] = rsqrtf((sred[0] + sred[1] + sred[2] + sred[3]) * (1.f / 1024.f));
    __syncthreads();
    const float r = sred[5];

    float4 o = {dx * r, dy * r, dz * r, dw * r};
    *(float4*)&out[(size_t)row * 1024 + tid * 4] = o;
}

extern "C" void kernel_launch(void* const* d_in, const int* in_sizes, int n_in,
                              void* d_out, int out_size, void* d_ws, size_t ws_size,
                              hipStream_t stream)
{
    const float* x     = (const float*)d_in[0];
    const int*   pmask = (const int*)  d_in[1];
    const float* Wq    = (const float*)d_in[2];
    const float* bq    = (const float*)d_in[3];
    const float* Wk    = (const float*)d_in[4];
    const float* bk    = (const float*)d_in[5];
    const float* Wv    = (const float*)d_in[6];
    const float* bv    = (const float*)d_in[7];
    const float* Wo    = (const float*)d_in[8];
    const float* bo    = (const float*)d_in[9];
    const float* rel   = (const float*)d_in[10];
    const float* W1    = (const float*)d_in[11];
    const float* b1    = (const float*)d_in[12];
    const float* W2    = (const float*)d_in[13];
    const float* b2    = (const float*)d_in[14];

    const int M = 4096, D = 1024, F = 4096;
    dim3 blk(256);
    dim3 gD(D / 64, M / 64);        // N=1024 gemms
    dim3 gH(2048 / 64, M / 64);     // N=2048 gemms (FFN half)

    // 48 MB workspace layout (16 MB slots); d_out doubles as att scratch.
    char* ws = (char*)d_ws;
    float* q      = (float*)(ws);                 // [0,16): q -> tmp -> ff2
    float* kk     = (float*)(ws + (16u << 20));   // [16,32): k -> attout
    float* vv     = (float*)(ws + (32u << 20));   // [32,48): v -> ff1 half (bf16)
    float* att    = (float*)d_out;                // att scratch, overwritten at end
    float* tmp    = q;
    float* attout = kk;
    bf16*  ff1h   = (bf16*)vv;
    float* ff2    = q;

    // QKV projections
    gemm_kernel<float, float, 0, 0><<<gD, blk, 0, stream>>>(x, D, Wq, D, bq, nullptr, q,  D, M, D, D);
    gemm_kernel<float, float, 0, 0><<<gD, blk, 0, stream>>>(x, D, Wk, D, bk, nullptr, kk, D, M, D, D);
    gemm_kernel<float, float, 0, 0><<<gD, blk, 0, stream>>>(x, D, Wv, D, bv, nullptr, vv, D, M, D, D);

    // attention (raw-reshape semantics: contiguous 64x(1024x64) batches)
    attn_kernel<<<dim3(1024, 64), blk, 0, stream>>>(q, kk, vv, rel, pmask, att);

    // att @ Wo.T + bo + x -> tmp; LN -> attout
    gemm_kernel<float, float, 0, 0><<<gD, blk, 0, stream>>>(att, D, Wo, D, bo, x, tmp, D, M, D, D);
    ln_kernel<<<4096, blk, 0, stream>>>(tmp, attout);

    // FFN chunked over F in halves of 2048 (ff1 half stored bf16)
    // half 0: ff1h = relu(attout @ W1[0:2048].T + b1[0:2048]); ff2 = ff1h @ W2[:,0:2048].T + b2
    gemm_kernel<float, bf16, 1, 0><<<gH, blk, 0, stream>>>(attout, D, W1, D, b1, nullptr, ff1h, 2048, M, 2048, D);
    gemm_kernel<bf16, float, 0, 0><<<gD, blk, 0, stream>>>(ff1h, 2048, W2, F, b2, nullptr, ff2, D, M, D, 2048);
    // half 1: ff1h = relu(attout @ W1[2048:4096].T + b1[2048:]); ff2 += ff1h @ W2[:,2048:].T + attout
    gemm_kernel<float, bf16, 1, 0><<<gH, blk, 0, stream>>>(attout, D, W1 + (size_t)2048 * D, D, b1 + 2048, nullptr, ff1h, 2048, M, 2048, D);
    gemm_kernel<bf16, float, 0, 1><<<gD, blk, 0, stream>>>(ff1h, 2048, W2 + 2048, F, nullptr, attout, ff2, D, M, D, 2048);

    // final LN -> d_out (fp32)
    ln_kernel<<<4096, blk, 0, stream>>>(ff2, (float*)d_out);
}

// Round 4
// 1650.505 us; speedup vs baseline: 3.0558x; 3.0558x over previous
//
#include <hip/hip_runtime.h>
#include <hip/hip_bf16.h>

typedef __hip_bfloat16 bf16;
typedef __attribute__((ext_vector_type(8))) short s8v;      // 8 bf16 (4 VGPRs) MFMA A/B frag
typedef __attribute__((ext_vector_type(4))) float f32x4;    // MFMA C/D frag

#define BM 64
#define BN 64
#define BK 16

__device__ __forceinline__ float bits2f(unsigned short u) {
    return __uint_as_float(((unsigned)u) << 16);
}
__device__ __forceinline__ unsigned short f2b(float f) {   // fp32 -> bf16 RNE
    union { float f; unsigned u; } x{f};
    return (unsigned short)((x.u + 0x7fff + ((x.u >> 16) & 1)) >> 16);
}

__device__ __forceinline__ void load4(const bf16* p, float* a) {
    ushort4 t = *(const ushort4*)p;
    a[0] = bits2f(t.x); a[1] = bits2f(t.y); a[2] = bits2f(t.z); a[3] = bits2f(t.w);
}
__device__ __forceinline__ void load4(const float* p, float* a) {
    float4 t = *(const float4*)p;
    a[0] = t.x; a[1] = t.y; a[2] = t.z; a[3] = t.w;
}

// ---------------- fp32 tiled GEMM (unchanged, proven) ----------------
// C[M,N] = A[M,K] @ W[N,K]^T (+bias) (+res) (+oldC if ADDC) (relu if RELU)
template<typename TA, typename TC, int RELU, int ADDC>
__global__ __launch_bounds__(256)
void gemm_kernel(const TA* __restrict__ A, int lda,
                 const float* __restrict__ W, int ldw,
                 const float* __restrict__ bias,
                 const float* __restrict__ res,
                 TC* __restrict__ C, int ldc,
                 int M, int N, int K)
{
    __shared__ float As[BK][BM + 4];
    __shared__ float Ws[BK][BN + 4];
    const int tid = threadIdx.x;
    const int ty = tid >> 4;
    const int tx = tid & 15;
    const int m0 = blockIdx.y * BM;
    const int n0 = blockIdx.x * BN;
    const int lmm = tid >> 2;
    const int lkk = (tid & 3) * 4;

    float acc[4][4] = {};

    for (int k0 = 0; k0 < K; k0 += BK) {
        float a[4], w[4];
        load4(A + (size_t)(m0 + lmm) * lda + k0 + lkk, a);
        load4(W + (size_t)(n0 + lmm) * ldw + k0 + lkk, w);
        __syncthreads();
        #pragma unroll
        for (int u = 0; u < 4; ++u) {
            As[lkk + u][lmm] = a[u];
            Ws[lkk + u][lmm] = w[u];
        }
        __syncthreads();
        #pragma unroll
        for (int kk = 0; kk < BK; ++kk) {
            float4 av = *(const float4*)&As[kk][ty * 4];
            float4 bv = *(const float4*)&Ws[kk][tx * 4];
            float am[4] = {av.x, av.y, av.z, av.w};
            float bn[4] = {bv.x, bv.y, bv.z, bv.w};
            #pragma unroll
            for (int i = 0; i < 4; ++i)
                #pragma unroll
                for (int j = 0; j < 4; ++j)
                    acc[i][j] += am[i] * bn[j];
        }
    }

    #pragma unroll
    for (int i = 0; i < 4; ++i) {
        int m = m0 + ty * 4 + i;
        #pragma unroll
        for (int j = 0; j < 4; ++j) {
            int n = n0 + tx * 4 + j;
            float c = acc[i][j];
            if (bias) c += bias[n];
            if (res)  c += res[(size_t)m * ldc + n];
            if (RELU) c = fmaxf(c, 0.f);
            if (ADDC) c += (float)C[(size_t)m * ldc + n];
            if (sizeof(TC) == 2) ((bf16*)C)[(size_t)m * ldc + n] = __float2bfloat16(c);
            else                 ((float*)C)[(size_t)m * ldc + n] = c;
        }
    }
}

// ---------------- T5 bucket table (double, matches numpy) ----------------
__global__ void bucket_kernel(unsigned char* __restrict__ bkt)
{
    int idx = blockIdx.x * 256 + threadIdx.x;   // over 1024*1024
    int i = idx >> 10, j = idx & 1023;
    int n = j - i;
    int ret = 0;
    if (n < 0) { ret = 16; n = -n; }
    int b;
    if (n < 8) b = n;
    else {
        double t = log((double)n / 8.0) / log(16.0) * 8.0;
        int v = 8 + (int)t;
        b = v < 15 ? v : 15;
    }
    bkt[idx] = (unsigned char)(ret + b);
}

// ---------------- fp32 -> bf16 convert ----------------
__global__ void cvt_kernel(const float* __restrict__ src, unsigned short* __restrict__ dst, int n4)
{
    int i = blockIdx.x * 256 + threadIdx.x;
    if (i < n4) {
        float4 v = ((const float4*)src)[i];
        ushort4 o = { f2b(v.x), f2b(v.y), f2b(v.z), f2b(v.w) };
        ((ushort4*)dst)[i] = o;
    }
}

// ---------------- V transpose: v fp32 [4096][1024] -> vt bf16 [bp][d][j] ----------------
// vt[bp*65536 + d*1024 + (mm*16 + c)] = v[(bp*64+mm)*1024 + c*64 + d]
__global__ __launch_bounds__(256)
void vtrans_kernel(const float* __restrict__ v, unsigned short* __restrict__ vt)
{
    __shared__ unsigned short t[64][68];
    const int bpmm = blockIdx.x;
    const int bp = bpmm >> 6, mm = bpmm & 63;
    const float* vr = v + (size_t)(bp * 64 + mm) * 1024;
    const int tid = threadIdx.x;
    #pragma unroll
    for (int it = 0; it < 4; ++it) {
        int c = (tid >> 6) + it * 4;   // 0..15
        int d = tid & 63;
        t[d][c] = f2b(vr[c * 64 + d]);
    }
    __syncthreads();
    int d = tid >> 2, qq = tid & 3;
    ushort4 o = { t[d][qq * 4 + 0], t[d][qq * 4 + 1], t[d][qq * 4 + 2], t[d][qq * 4 + 3] };
    *(ushort4*)(vt + (size_t)bp * 65536 + (size_t)d * 1024 + mm * 16 + qq * 4) = o;
}

// ---------------- MFMA flash attention ----------------
// grid (16, 64): 64-query tile per block, bp = blockIdx.y. 4 waves, wave w owns rows [w*16, w*16+16).
// All LDS tiles row-major [row][K-contig bf16], 16B chunks XOR-swizzled by (row & (chunks-1)).
__global__ __launch_bounds__(256, 2)
void attn_mfma_kernel(const unsigned short* __restrict__ qb,
                      const unsigned short* __restrict__ kb,
                      const unsigned short* __restrict__ vt,
                      const float* __restrict__ rel_emb,
                      const int* __restrict__ pmask,
                      const unsigned char* __restrict__ bkt,
                      unsigned short* __restrict__ att)
{
    __shared__ unsigned short Qs[64 * 64];     // 8KB  rows=query(64), 8 chunks
    __shared__ unsigned short Ks[128 * 64];    // 16KB rows=key(128),  8 chunks
    __shared__ unsigned short Vt[64 * 128];    // 16KB rows=d(64),    16 chunks
    __shared__ unsigned short Ps[4][16 * 128]; // 16KB per-wave P, rows=16, 16 chunks
    __shared__ float pml[1024];
    __shared__ float relh[32];

    const int tid = threadIdx.x;
    const int w = tid >> 6, lane = tid & 63;
    const int quad = lane >> 4, col = lane & 15;
    const int bp = blockIdx.y, i0 = blockIdx.x * 64;
    const int h = bp & 15, bb = bp >> 4;
    const size_t base = (size_t)bp << 16;
    const int myrow = w * 16;

    // stage Q (512 chunks), pml, relh
    {
        const unsigned short* qg = qb + base + (size_t)i0 * 64;
        #pragma unroll
        for (int it = 0; it < 2; ++it) {
            int idx = it * 256 + tid;
            int r = idx >> 3, c = idx & 7;
            s8v d = *(const s8v*)(qg + (size_t)r * 64 + (c ^ (r & 7)) * 8);
            *(s8v*)(Qs + r * 64 + c * 8) = d;
        }
    }
    #pragma unroll
    for (int it = 0; it < 4; ++it) {
        int j = it * 256 + tid;
        pml[j] = __logf((float)pmask[bb * 1024 + j]);
    }
    if (tid < 32) relh[tid] = rel_emb[tid * 16 + h];

    f32x4 O[4] = {};
    float mrow[4], lrow[4];
    #pragma unroll
    for (int r = 0; r < 4; ++r) { mrow[r] = -1e30f; lrow[r] = 0.f; }

    unsigned short* Pw = Ps[w];

    for (int jt = 0; jt < 8; ++jt) {
        const int j0 = jt * 128;
        __syncthreads();   // protect K/V LDS from readers of previous iter
        {   // stage Ks: 128 rows x 8 chunks
            const unsigned short* kg = kb + base + (size_t)j0 * 64;
            #pragma unroll
            for (int it = 0; it < 4; ++it) {
                int idx = it * 256 + tid;
                int r = idx >> 3, c = idx & 7;
                s8v d = *(const s8v*)(kg + (size_t)r * 64 + (c ^ (r & 7)) * 8);
                *(s8v*)(Ks + r * 64 + c * 8) = d;
            }
            // stage Vt: 64 rows x 16 chunks (global rows stride 1024 elems)
            const unsigned short* vg = vt + base + j0;
            #pragma unroll
            for (int it = 0; it < 4; ++it) {
                int idx = it * 256 + tid;
                int r = idx >> 4, c = idx & 15;
                s8v d = *(const s8v*)(vg + (size_t)r * 1024 + (c ^ (r & 15)) * 8);
                *(s8v*)(Vt + r * 128 + c * 8) = d;
            }
        }
        __syncthreads();

        // S = Q @ K^T : 1 row-tile x 8 col-tiles, K depth 64 (2 mfma steps)
        f32x4 S[8] = {};
        #pragma unroll
        for (int ks = 0; ks < 2; ++ks) {
            int ar = myrow + col;
            s8v a = *(const s8v*)(Qs + ar * 64 + (((ks * 4 + quad) ^ (ar & 7)) * 8));
            #pragma unroll
            for (int ct = 0; ct < 8; ++ct) {
                int br = ct * 16 + col;
                s8v b = *(const s8v*)(Ks + br * 64 + (((ks * 4 + quad) ^ (br & 7)) * 8));
                S[ct] = __builtin_amdgcn_mfma_f32_16x16x32_bf16(a, b, S[ct], 0, 0, 0);
            }
        }

        // bias + online softmax. C-layout: col = lane&15 (j), row = quad*4+reg (query).
        float newm[4];
        #pragma unroll
        for (int r = 0; r < 4; ++r) newm[r] = mrow[r];
        #pragma unroll
        for (int ct = 0; ct < 8; ++ct) {
            float pmv = pml[j0 + ct * 16 + col];
            int gj = j0 + ct * 16 + col;
            #pragma unroll
            for (int r = 0; r < 4; ++r) {
                int gr = i0 + myrow + quad * 4 + r;
                float s = S[ct][r] + relh[bkt[(size_t)gr * 1024 + gj]] + pmv;
                S[ct][r] = s;
                newm[r] = fmaxf(newm[r], s);
            }
        }
        #pragma unroll
        for (int off = 1; off < 16; off <<= 1)
            #pragma unroll
            for (int r = 0; r < 4; ++r)
                newm[r] = fmaxf(newm[r], __shfl_xor(newm[r], off));

        float alpha[4], lsum[4];
        #pragma unroll
        for (int r = 0; r < 4; ++r) { alpha[r] = __expf(mrow[r] - newm[r]); lsum[r] = 0.f; }
        #pragma unroll
        for (int ct = 0; ct < 8; ++ct)
            #pragma unroll
            for (int r = 0; r < 4; ++r) {
                float e = __expf(S[ct][r] - newm[r]);
                S[ct][r] = e;
                lsum[r] += e;
            }
        #pragma unroll
        for (int off = 1; off < 16; off <<= 1)
            #pragma unroll
            for (int r = 0; r < 4; ++r)
                lsum[r] += __shfl_xor(lsum[r], off);
        #pragma unroll
        for (int r = 0; r < 4; ++r) {
            lrow[r] = lrow[r] * alpha[r] + lsum[r];
            mrow[r] = newm[r];
        }
        #pragma unroll
        for (int nt = 0; nt < 4; ++nt)
            #pragma unroll
            for (int r = 0; r < 4; ++r)
                O[nt][r] *= alpha[r];

        // write P (bf16) to per-wave LDS, swizzled
        #pragma unroll
        for (int ct = 0; ct < 8; ++ct)
            #pragma unroll
            for (int r = 0; r < 4; ++r) {
                int lr = quad * 4 + r;
                int j = ct * 16 + col;
                Pw[lr * 128 + (((j >> 3) ^ lr) << 3) + (j & 7)] = f2b(S[ct][r]);
            }

        // O += P @ V : A=P rows (m=query local 0..15), B=Vt rows (n=d)
        #pragma unroll
        for (int kt = 0; kt < 4; ++kt) {
            int pr = col;
            s8v a = *(const s8v*)(Pw + pr * 128 + (((kt * 4 + quad) ^ pr) * 8));
            #pragma unroll
            for (int nt = 0; nt < 4; ++nt) {
                int vr = nt * 16 + col;
                s8v b = *(const s8v*)(Vt + vr * 128 + (((kt * 4 + quad) ^ (vr & 15)) * 8));
                O[nt] = __builtin_amdgcn_mfma_f32_16x16x32_bf16(a, b, O[nt], 0, 0, 0);
            }
        }
    }

    // normalize + store bf16
    #pragma unroll
    for (int r = 0; r < 4; ++r) lrow[r] = 1.f / lrow[r];
    unsigned short* ag = att + base + (size_t)(i0 + myrow) * 64;
    #pragma unroll
    for (int nt = 0; nt < 4; ++nt)
        #pragma unroll
        for (int r = 0; r < 4; ++r)
            ag[(size_t)(quad * 4 + r) * 64 + nt * 16 + col] = f2b(O[nt][r] * lrow[r]);
}

// ---------------- old scalar attention (fallback for small ws) ----------------
__global__ __launch_bounds__(256)
void attn_kernel(const float* __restrict__ q, const float* __restrict__ k,
                 const float* __restrict__ v, const float* __restrict__ rel_emb,
                 const int* __restrict__ pmask, float* __restrict__ att)
{
    const int i  = blockIdx.x;
    const int bp = blockIdx.y;
    const int h  = bp & 15;
    const int bb = bp >> 4;
    const int tid = threadIdx.x;

    __shared__ float qs[64];
    __shared__ float relh[32];
    __shared__ float pbuf[1024];
    __shared__ float red[4][64];
    __shared__ float sred[8];

    const size_t base = (size_t)bp * 65536;
    if (tid < 64) qs[tid] = q[base + (size_t)i * 64 + tid];
    if (tid < 32) relh[tid] = rel_emb[tid * 16 + h];
    __syncthreads();

    float s[4];
    float lmax = -1e30f;
    #pragma unroll
    for (int c = 0; c < 4; ++c) {
        int j = c * 256 + tid;
        const float* kr = k + base + (size_t)j * 64;
        float dot = 0.f;
        #pragma unroll
        for (int d = 0; d < 64; d += 4) {
            float4 kv = *(const float4*)&kr[d];
            dot += qs[d] * kv.x + qs[d+1] * kv.y + qs[d+2] * kv.z + qs[d+3] * kv.w;
        }
        int n = j - i, ret = 0;
        if (n < 0) { ret = 16; n = -n; }
        int b;
        if (n < 8) b = n;
        else {
            int vi = 8 + (int)(log2f((float)n * 0.125f) * 2.0f);
            b = vi < 15 ? vi : 15;
        }
        float pmv = (float)pmask[bb * 1024 + j];
        dot += relh[ret + b] + logf(pmv);
        s[c] = dot;
        lmax = fmaxf(lmax, dot);
    }

    const int lane = tid & 63, wid = tid >> 6;
    #pragma unroll
    for (int off = 32; off; off >>= 1) lmax = fmaxf(lmax, __shfl_down(lmax, off));
    if (lane == 0) sred[wid] = lmax;
    __syncthreads();
    if (tid == 0) sred[4] = fmaxf(fmaxf(sred[0], sred[1]), fmaxf(sred[2], sred[3]));
    __syncthreads();
    const float m = sred[4];

    float lsum = 0.f;
    #pragma unroll
    for (int c = 0; c < 4; ++c) {
        float e = expf(s[c] - m);
        pbuf[c * 256 + tid] = e;
        lsum += e;
    }
    #pragma unroll
    for (int off = 32; off; off >>= 1) lsum += __shfl_down(lsum, off);
    __syncthreads();
    if (lane == 0) sred[wid] = lsum;
    __syncthreads();
    if (tid == 0) sred[5] = sred[0] + sred[1] + sred[2] + sred[3];
    __syncthreads();
    const float inv = 1.f / sred[5];

    const int c2 = tid >> 6;
    const int d  = tid & 63;
    const float* vb = v + base;
    float partial = 0.f;
    for (int jj = 0; jj < 256; ++jj) {
        int j = c2 * 256 + jj;
        partial += pbuf[j] * vb[(size_t)j * 64 + d];
    }
    red[c2][d] = partial;
    __syncthreads();
    if (tid < 64) {
        float o = (red[0][tid] + red[1][tid] + red[2][tid] + red[3][tid]) * inv;
        att[base + (size_t)i * 64 + tid] = o;
    }
}

// ---------------- layernorm ----------------
__global__ __launch_bounds__(256)
void ln_kernel(const float* __restrict__ in, float* __restrict__ out)
{
    __shared__ float sred[8];
    const int row = blockIdx.x;
    const int tid = threadIdx.x;
    const float* rp = in + (size_t)row * 1024;
    float4 val = *(const float4*)&rp[tid * 4];

    float lsum = val.x + val.y + val.z + val.w;
    #pragma unroll
    for (int off = 32; off; off >>= 1) lsum += __shfl_down(lsum, off);
    const int lane = tid & 63, wid = tid >> 6;
    if (lane == 0) sred[wid] = lsum;
    __syncthreads();
    if (tid == 0) sred[4] = (sred[0] + sred[1] + sred[2] + sred[3]) * (1.f / 1024.f);
    __syncthreads();
    const float mean = sred[4];

    float dx = val.x - mean, dy = val.y - mean, dz = val.z - mean, dw = val.w - mean;
    float lsq = dx * dx + dy * dy + dz * dz + dw * dw;
    #pragma unroll
    for (int off = 32; off; off >>= 1) lsq += __shfl_down(lsq, off);
    __syncthreads();
    if (lane == 0) sred[wid] = lsq;
    __syncthreads();
    if (tid == 0) sred[5] = rsqrtf((sred[0] + sred[1] + sred[2] + sred[3]) * (1.f / 1024.f));
    __syncthreads();
    const float r = sred[5];

    float4 o = {dx * r, dy * r, dz * r, dw * r};
    *(float4*)&out[(size_t)row * 1024 + tid * 4] = o;
}

extern "C" void kernel_launch(void* const* d_in, const int* in_sizes, int n_in,
                              void* d_out, int out_size, void* d_ws, size_t ws_size,
                              hipStream_t stream)
{
    const float* x     = (const float*)d_in[0];
    const int*   pmask = (const int*)  d_in[1];
    const float* Wq    = (const float*)d_in[2];
    const float* bq    = (const float*)d_in[3];
    const float* Wk    = (const float*)d_in[4];
    const float* bk    = (const float*)d_in[5];
    const float* Wv    = (const float*)d_in[6];
    const float* bv    = (const float*)d_in[7];
    const float* Wo    = (const float*)d_in[8];
    const float* bo    = (const float*)d_in[9];
    const float* rel   = (const float*)d_in[10];
    const float* W1    = (const float*)d_in[11];
    const float* b1    = (const float*)d_in[12];
    const float* W2    = (const float*)d_in[13];
    const float* b2    = (const float*)d_in[14];

    const int M = 4096, D = 1024, F = 4096;
    dim3 blk(256);
    dim3 gD(D / 64, M / 64);
    dim3 gH(2048 / 64, M / 64);

    char* ws = (char*)d_ws;
    float* q   = (float*)(ws);
    float* kk  = (float*)(ws + (16u << 20));
    float* vv  = (float*)(ws + (32u << 20));

    // QKV projections (fp32)
    gemm_kernel<float, float, 0, 0><<<gD, blk, 0, stream>>>(x, D, Wq, D, bq, nullptr, q,  D, M, D, D);
    gemm_kernel<float, float, 0, 0><<<gD, blk, 0, stream>>>(x, D, Wk, D, bk, nullptr, kk, D, M, D, D);
    gemm_kernel<float, float, 0, 0><<<gD, blk, 0, stream>>>(x, D, Wv, D, bv, nullptr, vv, D, M, D, D);

    if (ws_size >= ((size_t)74 << 20)) {
        unsigned short* qb  = (unsigned short*)(ws + (48u << 20));
        unsigned short* kb  = (unsigned short*)(ws + (56u << 20));
        unsigned short* vt  = (unsigned short*)(ws + (64u << 20));
        unsigned char*  bkt = (unsigned char*) (ws + (72u << 20));

        cvt_kernel<<<4096, blk, 0, stream>>>(q,  qb, 1 << 20);
        cvt_kernel<<<4096, blk, 0, stream>>>(kk, kb, 1 << 20);
        vtrans_kernel<<<4096, blk, 0, stream>>>(vv, vt);
        bucket_kernel<<<4096, blk, 0, stream>>>(bkt);

        unsigned short* attb = (unsigned short*)d_out;   // bf16 att scratch
        attn_mfma_kernel<<<dim3(16, 64), blk, 0, stream>>>(qb, kb, vt, rel, pmask, bkt, attb);

        float* tmp    = q;
        float* attout = kk;
        bf16*  ff1h   = (bf16*)vv;
        float* ff2    = q;

        gemm_kernel<bf16, float, 0, 0><<<gD, blk, 0, stream>>>((const bf16*)attb, D, Wo, D, bo, x, tmp, D, M, D, D);
        ln_kernel<<<4096, blk, 0, stream>>>(tmp, attout);
        gemm_kernel<float, bf16, 1, 0><<<gH, blk, 0, stream>>>(attout, D, W1, D, b1, nullptr, ff1h, 2048, M, 2048, D);
        gemm_kernel<bf16, float, 0, 0><<<gD, blk, 0, stream>>>(ff1h, 2048, W2, F, b2, nullptr, ff2, D, M, D, 2048);
        gemm_kernel<float, bf16, 1, 0><<<gH, blk, 0, stream>>>(attout, D, W1 + (size_t)2048 * D, D, b1 + 2048, nullptr, ff1h, 2048, M, 2048, D);
        gemm_kernel<bf16, float, 0, 1><<<gD, blk, 0, stream>>>(ff1h, 2048, W2 + 2048, F, nullptr, attout, ff2, D, M, D, 2048);
        ln_kernel<<<4096, blk, 0, stream>>>(ff2, (float*)d_out);
    } else {
        // proven round-3 path
        float* att    = (float*)d_out;
        float* tmp    = q;
        float* attout = kk;
        bf16*  ff1h   = (bf16*)vv;
        float* ff2    = q;

        attn_kernel<<<dim3(1024, 64), blk, 0, stream>>>(q, kk, vv, rel, pmask, att);
        gemm_kernel<float, float, 0, 0><<<gD, blk, 0, stream>>>(att, D, Wo, D, bo, x, tmp, D, M, D, D);
        ln_kernel<<<4096, blk, 0, stream>>>(tmp, attout);
        gemm_kernel<float, bf16, 1, 0><<<gH, blk, 0, stream>>>(attout, D, W1, D, b1, nullptr, ff1h, 2048, M, 2048, D);
        gemm_kernel<bf16, float, 0, 0><<<gD, blk, 0, stream>>>(ff1h, 2048, W2, F, b2, nullptr, ff2, D, M, D, 2048);
        gemm_kernel<float, bf16, 1, 0><<<gH, blk, 0, stream>>>(attout, D, W1 + (size_t)2048 * D, D, b1 + 2048, nullptr, ff1h, 2048, M, 2048, D);
        gemm_kernel<bf16, float, 0, 1><<<gD, blk, 0, stream>>>(ff1h, 2048, W2 + 2048, F, nullptr, attout, ff2, D, M, D, 2048);
        ln_kernel<<<4096, blk, 0, stream>>>(ff2, (float*)d_out);
    }
}

// Round 5
// 589.598 us; speedup vs baseline: 8.5542x; 2.7994x over previous
//
#include <hip/hip_runtime.h>
#include <hip/hip_bf16.h>

typedef __hip_bfloat16 bf16;
typedef __attribute__((ext_vector_type(8))) short s8v;      // 8 bf16 (4 VGPRs) MFMA A/B frag
typedef __attribute__((ext_vector_type(4))) float f32x4;    // MFMA C/D frag

__device__ __forceinline__ unsigned short f2b(float f) {   // fp32 -> bf16 RNE
    union { float f; unsigned u; } x{f};
    return (unsigned short)((x.u + 0x7fff + ((x.u >> 16) & 1)) >> 16);
}

// ---------------- fp32 -> bf16 convert ----------------
__global__ __launch_bounds__(256)
void cvt_kernel(const float* __restrict__ src, unsigned short* __restrict__ dst, int n4)
{
    int i = blockIdx.x * 256 + threadIdx.x;
    if (i < n4) {
        float4 v = ((const float4*)src)[i];
        ushort4 o = { f2b(v.x), f2b(v.y), f2b(v.z), f2b(v.w) };
        ((ushort4*)dst)[i] = o;
    }
}

// ---------------- T5 bucket table (double, matches numpy) ----------------
__global__ void bucket_kernel(unsigned char* __restrict__ bkt)
{
    int idx = blockIdx.x * 256 + threadIdx.x;   // over 1024*1024
    int i = idx >> 10, j = idx & 1023;
    int n = j - i;
    int ret = 0;
    if (n < 0) { ret = 16; n = -n; }
    int b;
    if (n < 8) b = n;
    else {
        double t = log((double)n / 8.0) / log(16.0) * 8.0;
        int v = 8 + (int)t;
        b = v < 15 ? v : 15;
    }
    bkt[idx] = (unsigned char)(ret + b);
}

// ---------------- MFMA GEMM: C[M,N] = A[M,K] @ W[N,K]^T (+bias)(+res)(+C)(relu) ----------------
// A, W bf16 row-major (K contiguous). 128x128 block tile, BK=32, 4 waves in 2x2 (64x64/wave).
// LDS tiles [128 rows][4 chunks of 8 bf16]; chunk position p holds global chunk p ^ ((row>>2)&3)
// so fragment ds_read_b128s are <=2-way bank-aliased (free). Staged with global_load_lds width 16.
template<typename TC, int RELU, int ADDC>
__global__ __launch_bounds__(256)
void mfma_gemm(const unsigned short* __restrict__ A, int lda,
               const unsigned short* __restrict__ W, int ldw,
               const float* __restrict__ bias,
               const float* __restrict__ res,
               void* __restrict__ Cv, int ldc,
               int M, int N, int K)
{
    __shared__ unsigned short sm[2 * 128 * 32];   // As | Ws, 8KB each
    unsigned short* As = sm;
    unsigned short* Ws = sm + 128 * 32;

    const int tid = threadIdx.x;
    const int w = tid >> 6, lane = tid & 63;
    const int quad = lane >> 4, col = lane & 15;
    const int m0 = blockIdx.y * 128, n0 = blockIdx.x * 128;
    const int wrow = (w & 1) * 64, wcol = (w >> 1) * 64;

    const int srow   = lane >> 2;                         // row within 16-row group
    const int schunk = (lane & 3) ^ ((lane >> 4) & 3);    // swizzled global chunk

    f32x4 acc[4][4] = {};

    for (int k0 = 0; k0 < K; k0 += 32) {
        __syncthreads();   // protect LDS from previous iter's readers
        #pragma unroll
        for (int t = 0; t < 2; ++t) {
            const int rbase = w * 32 + t * 16;
            unsigned off = (unsigned)(rbase * 64);
            off = __builtin_amdgcn_readfirstlane(off);
            const unsigned short* ga = A + (size_t)(m0 + rbase + srow) * lda + k0 + schunk * 8;
            __builtin_amdgcn_global_load_lds(
                (const __attribute__((address_space(1))) unsigned int*)ga,
                (__attribute__((address_space(3))) unsigned int*)((char*)As + off), 16, 0, 0);
            const unsigned short* gw = W + (size_t)(n0 + rbase + srow) * ldw + k0 + schunk * 8;
            __builtin_amdgcn_global_load_lds(
                (const __attribute__((address_space(1))) unsigned int*)gw,
                (__attribute__((address_space(3))) unsigned int*)((char*)Ws + off), 16, 0, 0);
        }
        __syncthreads();   // drain vmcnt (compiler) + all waves staged

        s8v af[4], bfr[4];
        #pragma unroll
        for (int mt = 0; mt < 4; ++mt) {
            int rr = wrow + mt * 16 + col;
            af[mt] = *(const s8v*)(As + rr * 32 + ((quad ^ ((rr >> 2) & 3)) * 8));
        }
        #pragma unroll
        for (int nt = 0; nt < 4; ++nt) {
            int rr = wcol + nt * 16 + col;
            bfr[nt] = *(const s8v*)(Ws + rr * 32 + ((quad ^ ((rr >> 2) & 3)) * 8));
        }
        #pragma unroll
        for (int mt = 0; mt < 4; ++mt)
            #pragma unroll
            for (int nt = 0; nt < 4; ++nt)
                acc[mt][nt] = __builtin_amdgcn_mfma_f32_16x16x32_bf16(af[mt], bfr[nt], acc[mt][nt], 0, 0, 0);
    }

    // epilogue: C/D layout col=lane&15, row=quad*4+reg
    #pragma unroll
    for (int mt = 0; mt < 4; ++mt) {
        #pragma unroll
        for (int rg = 0; rg < 4; ++rg) {
            int gm = m0 + wrow + mt * 16 + quad * 4 + rg;
            #pragma unroll
            for (int nt = 0; nt < 4; ++nt) {
                int gn = n0 + wcol + nt * 16 + col;
                float c = acc[mt][nt][rg];
                if (bias) c += bias[gn];
                if (res)  c += res[(size_t)gm * ldc + gn];
                if (RELU) c = fmaxf(c, 0.f);
                if (ADDC) c += ((const float*)Cv)[(size_t)gm * ldc + gn];
                if (sizeof(TC) == 2) ((unsigned short*)Cv)[(size_t)gm * ldc + gn] = f2b(c);
                else                 ((float*)Cv)[(size_t)gm * ldc + gn] = c;
            }
        }
    }
}

// ---------------- V transpose: vb bf16 [4096][1024] -> vt bf16 [bp][d][j] ----------------
__global__ __launch_bounds__(256)
void vtrans_kernel(const unsigned short* __restrict__ v, unsigned short* __restrict__ vt)
{
    __shared__ unsigned short t[64][68];
    const int bpmm = blockIdx.x;
    const int bp = bpmm >> 6, mm = bpmm & 63;
    const unsigned short* vr = v + (size_t)(bp * 64 + mm) * 1024;
    const int tid = threadIdx.x;
    #pragma unroll
    for (int it = 0; it < 4; ++it) {
        int c = (tid >> 6) + it * 4;   // 0..15
        int d = tid & 63;
        t[d][c] = vr[c * 64 + d];
    }
    __syncthreads();
    int d = tid >> 2, qq = tid & 3;
    ushort4 o = { t[d][qq * 4 + 0], t[d][qq * 4 + 1], t[d][qq * 4 + 2], t[d][qq * 4 + 3] };
    *(ushort4*)(vt + (size_t)bp * 65536 + (size_t)d * 1024 + mm * 16 + qq * 4) = o;
}

// ---------------- MFMA flash attention (proven round 4) ----------------
__global__ __launch_bounds__(256, 2)
void attn_mfma_kernel(const unsigned short* __restrict__ qb,
                      const unsigned short* __restrict__ kb,
                      const unsigned short* __restrict__ vt,
                      const float* __restrict__ rel_emb,
                      const int* __restrict__ pmask,
                      const unsigned char* __restrict__ bkt,
                      unsigned short* __restrict__ att)
{
    __shared__ unsigned short Qs[64 * 64];
    __shared__ unsigned short Ks[128 * 64];
    __shared__ unsigned short Vt[64 * 128];
    __shared__ unsigned short Ps[4][16 * 128];
    __shared__ float pml[1024];
    __shared__ float relh[32];

    const int tid = threadIdx.x;
    const int w = tid >> 6, lane = tid & 63;
    const int quad = lane >> 4, col = lane & 15;
    const int bp = blockIdx.y, i0 = blockIdx.x * 64;
    const int h = bp & 15, bb = bp >> 4;
    const size_t base = (size_t)bp << 16;
    const int myrow = w * 16;

    {
        const unsigned short* qg = qb + base + (size_t)i0 * 64;
        #pragma unroll
        for (int it = 0; it < 2; ++it) {
            int idx = it * 256 + tid;
            int r = idx >> 3, c = idx & 7;
            s8v d = *(const s8v*)(qg + (size_t)r * 64 + (c ^ (r & 7)) * 8);
            *(s8v*)(Qs + r * 64 + c * 8) = d;
        }
    }
    #pragma unroll
    for (int it = 0; it < 4; ++it) {
        int j = it * 256 + tid;
        pml[j] = __logf((float)pmask[bb * 1024 + j]);
    }
    if (tid < 32) relh[tid] = rel_emb[tid * 16 + h];

    f32x4 O[4] = {};
    float mrow[4], lrow[4];
    #pragma unroll
    for (int r = 0; r < 4; ++r) { mrow[r] = -1e30f; lrow[r] = 0.f; }

    unsigned short* Pw = Ps[w];

    for (int jt = 0; jt < 8; ++jt) {
        const int j0 = jt * 128;
        __syncthreads();
        {
            const unsigned short* kg = kb + base + (size_t)j0 * 64;
            #pragma unroll
            for (int it = 0; it < 4; ++it) {
                int idx = it * 256 + tid;
                int r = idx >> 3, c = idx & 7;
                s8v d = *(const s8v*)(kg + (size_t)r * 64 + (c ^ (r & 7)) * 8);
                *(s8v*)(Ks + r * 64 + c * 8) = d;
            }
            const unsigned short* vg = vt + base + j0;
            #pragma unroll
            for (int it = 0; it < 4; ++it) {
                int idx = it * 256 + tid;
                int r = idx >> 4, c = idx & 15;
                s8v d = *(const s8v*)(vg + (size_t)r * 1024 + (c ^ (r & 15)) * 8);
                *(s8v*)(Vt + r * 128 + c * 8) = d;
            }
        }
        __syncthreads();

        f32x4 S[8] = {};
        #pragma unroll
        for (int ks = 0; ks < 2; ++ks) {
            int ar = myrow + col;
            s8v a = *(const s8v*)(Qs + ar * 64 + (((ks * 4 + quad) ^ (ar & 7)) * 8));
            #pragma unroll
            for (int ct = 0; ct < 8; ++ct) {
                int br = ct * 16 + col;
                s8v b = *(const s8v*)(Ks + br * 64 + (((ks * 4 + quad) ^ (br & 7)) * 8));
                S[ct] = __builtin_amdgcn_mfma_f32_16x16x32_bf16(a, b, S[ct], 0, 0, 0);
            }
        }

        float newm[4];
        #pragma unroll
        for (int r = 0; r < 4; ++r) newm[r] = mrow[r];
        #pragma unroll
        for (int ct = 0; ct < 8; ++ct) {
            float pmv = pml[j0 + ct * 16 + col];
            int gj = j0 + ct * 16 + col;
            #pragma unroll
            for (int r = 0; r < 4; ++r) {
                int gr = i0 + myrow + quad * 4 + r;
                float s = S[ct][r] + relh[bkt[(size_t)gr * 1024 + gj]] + pmv;
                S[ct][r] = s;
                newm[r] = fmaxf(newm[r], s);
            }
        }
        #pragma unroll
        for (int off = 1; off < 16; off <<= 1)
            #pragma unroll
            for (int r = 0; r < 4; ++r)
                newm[r] = fmaxf(newm[r], __shfl_xor(newm[r], off));

        float alpha[4], lsum[4];
        #pragma unroll
        for (int r = 0; r < 4; ++r) { alpha[r] = __expf(mrow[r] - newm[r]); lsum[r] = 0.f; }
        #pragma unroll
        for (int ct = 0; ct < 8; ++ct)
            #pragma unroll
            for (int r = 0; r < 4; ++r) {
                float e = __expf(S[ct][r] - newm[r]);
                S[ct][r] = e;
                lsum[r] += e;
            }
        #pragma unroll
        for (int off = 1; off < 16; off <<= 1)
            #pragma unroll
            for (int r = 0; r < 4; ++r)
                lsum[r] += __shfl_xor(lsum[r], off);
        #pragma unroll
        for (int r = 0; r < 4; ++r) {
            lrow[r] = lrow[r] * alpha[r] + lsum[r];
            mrow[r] = newm[r];
        }
        #pragma unroll
        for (int nt = 0; nt < 4; ++nt)
            #pragma unroll
            for (int r = 0; r < 4; ++r)
                O[nt][r] *= alpha[r];

        #pragma unroll
        for (int ct = 0; ct < 8; ++ct)
            #pragma unroll
            for (int r = 0; r < 4; ++r) {
                int lr = quad * 4 + r;
                int j = ct * 16 + col;
                Pw[lr * 128 + (((j >> 3) ^ lr) << 3) + (j & 7)] = f2b(S[ct][r]);
            }

        #pragma unroll
        for (int kt = 0; kt < 4; ++kt) {
            int pr = col;
            s8v a = *(const s8v*)(Pw + pr * 128 + (((kt * 4 + quad) ^ pr) * 8));
            #pragma unroll
            for (int nt = 0; nt < 4; ++nt) {
                int vr = nt * 16 + col;
                s8v b = *(const s8v*)(Vt + vr * 128 + (((kt * 4 + quad) ^ (vr & 15)) * 8));
                O[nt] = __builtin_amdgcn_mfma_f32_16x16x32_bf16(a, b, O[nt], 0, 0, 0);
            }
        }
    }

    #pragma unroll
    for (int r = 0; r < 4; ++r) lrow[r] = 1.f / lrow[r];
    unsigned short* ag = att + base + (size_t)(i0 + myrow) * 64;
    #pragma unroll
    for (int nt = 0; nt < 4; ++nt)
        #pragma unroll
        for (int r = 0; r < 4; ++r)
            ag[(size_t)(quad * 4 + r) * 64 + nt * 16 + col] = f2b(O[nt][r] * lrow[r]);
}

// ---------------- layernorm (fp32 out; optional extra bf16 out) ----------------
__global__ __launch_bounds__(256)
void ln_kernel(const float* __restrict__ in, float* __restrict__ outF,
               unsigned short* __restrict__ outB)
{
    __shared__ float sred[8];
    const int row = blockIdx.x;
    const int tid = threadIdx.x;
    const float* rp = in + (size_t)row * 1024;
    float4 val = *(const float4*)&rp[tid * 4];

    float lsum = val.x + val.y + val.z + val.w;
    #pragma unroll
    for (int off = 32; off; off >>= 1) lsum += __shfl_down(lsum, off);
    const int lane = tid & 63, wid = tid >> 6;
    if (lane == 0) sred[wid] = lsum;
    __syncthreads();
    if (tid == 0) sred[4] = (sred[0] + sred[1] + sred[2] + sred[3]) * (1.f / 1024.f);
    __syncthreads();
    const float mean = sred[4];

    float dx = val.x - mean, dy = val.y - mean, dz = val.z - mean, dw = val.w - mean;
    float lsq = dx * dx + dy * dy + dz * dz + dw * dw;
    #pragma unroll
    for (int off = 32; off; off >>= 1) lsq += __shfl_down(lsq, off);
    __syncthreads();
    if (lane == 0) sred[wid] = lsq;
    __syncthreads();
    if (tid == 0) sred[5] = rsqrtf((sred[0] + sred[1] + sred[2] + sred[3]) * (1.f / 1024.f));
    __syncthreads();
    const float r = sred[5];

    float ox = dx * r, oy = dy * r, oz = dz * r, ow = dw * r;
    if (outF) {
        float4 o = {ox, oy, oz, ow};
        *(float4*)&outF[(size_t)row * 1024 + tid * 4] = o;
    }
    if (outB) {
        ushort4 o = { f2b(ox), f2b(oy), f2b(oz), f2b(ow) };
        *(ushort4*)&outB[(size_t)row * 1024 + tid * 4] = o;
    }
}

extern "C" void kernel_launch(void* const* d_in, const int* in_sizes, int n_in,
                              void* d_out, int out_size, void* d_ws, size_t ws_size,
                              hipStream_t stream)
{
    const float* x     = (const float*)d_in[0];
    const int*   pmask = (const int*)  d_in[1];
    const float* Wq    = (const float*)d_in[2];
    const float* bq    = (const float*)d_in[3];
    const float* Wk    = (const float*)d_in[4];
    const float* bk    = (const float*)d_in[5];
    const float* Wv    = (const float*)d_in[6];
    const float* bv    = (const float*)d_in[7];
    const float* Wo    = (const float*)d_in[8];
    const float* bo    = (const float*)d_in[9];
    const float* rel   = (const float*)d_in[10];
    const float* W1    = (const float*)d_in[11];
    const float* b1    = (const float*)d_in[12];
    const float* W2    = (const float*)d_in[13];
    const float* b2    = (const float*)d_in[14];

    const int M = 4096, D = 1024;
    dim3 blk(256);

    // ---- workspace map (MB offsets, peak 65 MB; round 4 proved ws >= 74 MB) ----
    char* ws = (char*)d_ws;
    unsigned short* xb   = (unsigned short*)(ws);                 // 0-8
    unsigned short* qb   = (unsigned short*)(ws + ( 8u << 20));   // 8-16
    unsigned short* kb   = (unsigned short*)(ws + (16u << 20));   // 16-24
    unsigned short* vb   = (unsigned short*)(ws + (24u << 20));   // 24-32
    unsigned short* vt   = (unsigned short*)(ws + (32u << 20));   // 32-40
    unsigned short* Wqb  = (unsigned short*)(ws + (40u << 20));   // 40-42
    unsigned short* Wkb  = (unsigned short*)(ws + (42u << 20));   // 42-44
    unsigned short* Wvb  = (unsigned short*)(ws + (44u << 20));   // 44-46
    unsigned short* Wob  = (unsigned short*)(ws + (46u << 20));   // 46-48
    unsigned short* W1b  = (unsigned short*)(ws + (48u << 20));   // 48-56
    unsigned short* W2b  = (unsigned short*)(ws + (56u << 20));   // 56-64
    unsigned char*  bkt  = (unsigned char*) (ws + (64u << 20));   // 64-65
    // phase-2 reuse:
    float*          tmp     = (float*)(ws + (8u << 20));          // 8-24  (qb/kb dead)
    float*          attoutF = (float*)(ws + (32u << 20));         // 32-48 (vt, W*b dead)
    unsigned short* attoutB = (unsigned short*)(ws);              // 0-8   (xb dead)
    unsigned short* ff1h    = (unsigned short*)(ws + (8u << 20)); // 8-24  (tmp dead)
    float*          ff2     = attoutF;                            // in-place residual
    unsigned short* attb    = (unsigned short*)d_out;             // bf16 att scratch (overwritten by ln2)

    // ---- bf16 conversions ----
    cvt_kernel<<<4096, blk, 0, stream>>>(x,  xb,  1 << 20);
    cvt_kernel<<<1024, blk, 0, stream>>>(Wq, Wqb, 1 << 18);
    cvt_kernel<<<1024, blk, 0, stream>>>(Wk, Wkb, 1 << 18);
    cvt_kernel<<<1024, blk, 0, stream>>>(Wv, Wvb, 1 << 18);
    cvt_kernel<<<1024, blk, 0, stream>>>(Wo, Wob, 1 << 18);
    cvt_kernel<<<4096, blk, 0, stream>>>(W1, W1b, 1 << 20);
    cvt_kernel<<<4096, blk, 0, stream>>>(W2, W2b, 1 << 20);
    bucket_kernel<<<4096, blk, 0, stream>>>(bkt);

    // ---- QKV projections (bf16 MFMA, bf16 out) ----
    dim3 gD(D / 128, M / 128);       // (8,32)
    mfma_gemm<unsigned short, 0, 0><<<gD, blk, 0, stream>>>(xb, D, Wqb, D, bq, nullptr, qb, D, M, D, D);
    mfma_gemm<unsigned short, 0, 0><<<gD, blk, 0, stream>>>(xb, D, Wkb, D, bk, nullptr, kb, D, M, D, D);
    mfma_gemm<unsigned short, 0, 0><<<gD, blk, 0, stream>>>(xb, D, Wvb, D, bv, nullptr, vb, D, M, D, D);

    vtrans_kernel<<<4096, blk, 0, stream>>>(vb, vt);

    // ---- attention ----
    attn_mfma_kernel<<<dim3(16, 64), blk, 0, stream>>>(qb, kb, vt, rel, pmask, bkt, attb);

    // ---- Wo projection + residual(x fp32) -> tmp fp32; LN1 -> attoutF + attoutB ----
    mfma_gemm<float, 0, 0><<<gD, blk, 0, stream>>>(attb, D, Wob, D, bo, x, tmp, D, M, D, D);
    ln_kernel<<<4096, blk, 0, stream>>>(tmp, attoutF, attoutB);

    // ---- FFN, F chunked in halves of 2048 ----
    dim3 gH(2048 / 128, M / 128);    // (16,32)
    // half 0
    mfma_gemm<unsigned short, 1, 0><<<gH, blk, 0, stream>>>(attoutB, D, W1b, D, b1, nullptr, ff1h, 2048, M, 2048, D);
    mfma_gemm<float, 0, 0><<<gD, blk, 0, stream>>>(ff1h, 2048, W2b, 4096, b2, attoutF, ff2, D, M, D, 2048);
    // half 1
    mfma_gemm<unsigned short, 1, 0><<<gH, blk, 0, stream>>>(attoutB, D, W1b + (size_t)2048 * D, D, b1 + 2048, nullptr, ff1h, 2048, M, 2048, D);
    mfma_gemm<float, 0, 1><<<gD, blk, 0, stream>>>(ff1h, 2048, W2b + 2048, 4096, nullptr, nullptr, ff2, D, M, D, 2048);

    // ---- final LN -> d_out (fp32) ----
    ln_kernel<<<4096, blk, 0, stream>>>(ff2, (float*)d_out, nullptr);
}

// Round 7
// 472.572 us; speedup vs baseline: 10.6726x; 1.2476x over previous
//
#include <hip/hip_runtime.h>
#include <hip/hip_bf16.h>

typedef __hip_bfloat16 bf16;
typedef __attribute__((ext_vector_type(8))) short s8v;      // 8 bf16 (4 VGPRs) MFMA A/B frag
typedef __attribute__((ext_vector_type(4))) float f32x4;    // MFMA C/D frag

__device__ __forceinline__ float bits2f(unsigned short u) {
    return __uint_as_float(((unsigned)u) << 16);
}
__device__ __forceinline__ unsigned short f2b(float f) {   // fp32 -> bf16 RNE
    union { float f; unsigned u; } x{f};
    return (unsigned short)((x.u + 0x7fff + ((x.u >> 16) & 1)) >> 16);
}
__device__ __forceinline__ float to_f(float x) { return x; }
__device__ __forceinline__ float to_f(unsigned short x) { return bits2f(x); }

__device__ __forceinline__ void load4(const float* p, float* a) {
    float4 t = *(const float4*)p;
    a[0] = t.x; a[1] = t.y; a[2] = t.z; a[3] = t.w;
}
__device__ __forceinline__ void load4(const unsigned short* p, float* a) {
    ushort4 t = *(const ushort4*)p;
    a[0] = bits2f(t.x); a[1] = bits2f(t.y); a[2] = bits2f(t.z); a[3] = bits2f(t.w);
}

// ---------------- fp32 -> bf16 convert ----------------
__global__ __launch_bounds__(256)
void cvt_kernel(const float* __restrict__ src, unsigned short* __restrict__ dst, int n4)
{
    int i = blockIdx.x * 256 + threadIdx.x;
    if (i < n4) {
        float4 v = ((const float4*)src)[i];
        ushort4 o = { f2b(v.x), f2b(v.y), f2b(v.z), f2b(v.w) };
        ((ushort4*)dst)[i] = o;
    }
}

// ---------------- per-head relative-position bias by delta (T5 buckets, double math) ----------------
// rbias[h*2048 + (delta+1023)] = rel_emb[bucket(j-i=delta)][h], bf16
__global__ void rbias_kernel(const float* __restrict__ rel_emb, unsigned short* __restrict__ rbias)
{
    int idx = blockIdx.x * 256 + threadIdx.x;   // 16 * 2048
    if (idx >= 16 * 2048) return;
    int h = idx >> 11, q = idx & 2047;
    int n = q - 1023, ret = 0;                  // n = j - i
    if (n < 0) { ret = 16; n = -n; }
    int b;
    if (n < 8) b = n;
    else {
        double t = log((double)n / 8.0) / log(16.0) * 8.0;
        int v = 8 + (int)t;
        b = v < 15 ? v : 15;
    }
    rbias[idx] = f2b(rel_emb[(ret + b) * 16 + h]);
}

// ---------------- MFMA GEMM ----------------
// C = A[M,K] @ W[N,K]^T (+bias)(+res)(relu), A/W bf16 row-major. 128x128 tile, BK=32,
// 4 waves 2x2. LDS chunk-XOR swizzle (<=2-way conflicts, free). global_load_lds width 16.
// QKV=1: N spans 3 concatenated 1024-wide outputs routed to C0/C1/C2 with bias b0/b1/b2.
// gridDim.z=2: split-K; z selects K-half and C0(z=0)/C1(z=1); bias/res applied at z=0 only.
// TR = residual element type (float or bf16-as-ushort).
template<typename TC, typename TR, int RELU, int QKV>
__global__ __launch_bounds__(256)
void mfma_gemm(const unsigned short* __restrict__ A, int lda,
               const unsigned short* __restrict__ W, int ldw,
               const float* __restrict__ b0, const float* __restrict__ b1,
               const float* __restrict__ b2,
               const TR* __restrict__ res,
               void* __restrict__ C0, void* __restrict__ C1, void* __restrict__ C2,
               int ldc, int M, int N, int Ksplit)
{
    __shared__ unsigned short sm[2 * 128 * 32];
    unsigned short* As = sm;
    unsigned short* Ws = sm + 128 * 32;

    const int tid = threadIdx.x;
    const int w = tid >> 6, lane = tid & 63;
    const int quad = lane >> 4, col = lane & 15;
    const int m0 = blockIdx.y * 128, n0 = blockIdx.x * 128;
    const int wrow = (w & 1) * 64, wcol = (w >> 1) * 64;
    const int kz = blockIdx.z * Ksplit;

    const int srow   = lane >> 2;
    const int schunk = (lane & 3) ^ ((lane >> 4) & 3);

    f32x4 acc[4][4] = {};

    for (int k0 = kz; k0 < kz + Ksplit; k0 += 32) {
        __syncthreads();
        #pragma unroll
        for (int t = 0; t < 2; ++t) {
            const int rbase = w * 32 + t * 16;
            unsigned off = (unsigned)(rbase * 64);
            off = __builtin_amdgcn_readfirstlane(off);
            const unsigned short* ga = A + (size_t)(m0 + rbase + srow) * lda + k0 + schunk * 8;
            __builtin_amdgcn_global_load_lds(
                (const __attribute__((address_space(1))) unsigned int*)ga,
                (__attribute__((address_space(3))) unsigned int*)((char*)As + off), 16, 0, 0);
            const unsigned short* gw = W + (size_t)(n0 + rbase + srow) * ldw + k0 + schunk * 8;
            __builtin_amdgcn_global_load_lds(
                (const __attribute__((address_space(1))) unsigned int*)gw,
                (__attribute__((address_space(3))) unsigned int*)((char*)Ws + off), 16, 0, 0);
        }
        __syncthreads();

        s8v af[4], bfr[4];
        #pragma unroll
        for (int mt = 0; mt < 4; ++mt) {
            int rr = wrow + mt * 16 + col;
            af[mt] = *(const s8v*)(As + rr * 32 + ((quad ^ ((rr >> 2) & 3)) * 8));
        }
        #pragma unroll
        for (int nt = 0; nt < 4; ++nt) {
            int rr = wcol + nt * 16 + col;
            bfr[nt] = *(const s8v*)(Ws + rr * 32 + ((quad ^ ((rr >> 2) & 3)) * 8));
        }
        #pragma unroll
        for (int mt = 0; mt < 4; ++mt)
            #pragma unroll
            for (int nt = 0; nt < 4; ++nt)
                acc[mt][nt] = __builtin_amdgcn_mfma_f32_16x16x32_bf16(af[mt], bfr[nt], acc[mt][nt], 0, 0, 0);
    }

    // epilogue (C/D layout: col=lane&15, row=quad*4+reg)
    if (QKV) {
        const int sel = n0 >> 10;
        unsigned short* Cb = (unsigned short*)(sel == 0 ? C0 : sel == 1 ? C1 : C2);
        const float* bs = sel == 0 ? b0 : sel == 1 ? b1 : b2;
        #pragma unroll
        for (int mt = 0; mt < 4; ++mt)
            #pragma unroll
            for (int rg = 0; rg < 4; ++rg) {
                int gm = m0 + wrow + mt * 16 + quad * 4 + rg;
                #pragma unroll
                for (int nt = 0; nt < 4; ++nt) {
                    int gnc = (n0 + wcol + nt * 16 + col) & 1023;
                    Cb[(size_t)gm * 1024 + gnc] = f2b(acc[mt][nt][rg] + bs[gnc]);
                }
            }
    } else {
        void* Cv = blockIdx.z ? C1 : C0;
        const bool z0 = (blockIdx.z == 0);
        #pragma unroll
        for (int mt = 0; mt < 4; ++mt)
            #pragma unroll
            for (int rg = 0; rg < 4; ++rg) {
                int gm = m0 + wrow + mt * 16 + quad * 4 + rg;
                #pragma unroll
                for (int nt = 0; nt < 4; ++nt) {
                    int gn = n0 + wcol + nt * 16 + col;
                    float c = acc[mt][nt][rg];
                    if (z0) {
                        if (b0)  c += b0[gn];
                        if (res) c += to_f(res[(size_t)gm * ldc + gn]);
                    }
                    if (RELU) c = fmaxf(c, 0.f);
                    if (sizeof(TC) == 2) ((unsigned short*)Cv)[(size_t)gm * ldc + gn] = f2b(c);
                    else                 ((float*)Cv)[(size_t)gm * ldc + gn] = c;
                }
            }
    }
}

// ---------------- V transpose: vb bf16 [4096][1024] -> vt bf16 [bp][d][j] ----------------
__global__ __launch_bounds__(256)
void vtrans_kernel(const unsigned short* __restrict__ v, unsigned short* __restrict__ vt)
{
    __shared__ unsigned short t[64][68];
    const int bpmm = blockIdx.x;
    const int bp = bpmm >> 6, mm = bpmm & 63;
    const unsigned short* vr = v + (size_t)(bp * 64 + mm) * 1024;
    const int tid = threadIdx.x;
    #pragma unroll
    for (int it = 0; it < 4; ++it) {
        int c = (tid >> 6) + it * 4;
        int d = tid & 63;
        t[d][c] = vr[c * 64 + d];
    }
    __syncthreads();
    int d = tid >> 2, qq = tid & 3;
    ushort4 o = { t[d][qq * 4 + 0], t[d][qq * 4 + 1], t[d][qq * 4 + 2], t[d][qq * 4 + 3] };
    *(ushort4*)(vt + (size_t)bp * 65536 + (size_t)d * 1024 + mm * 16 + qq * 4) = o;
}

// ---------------- MFMA flash attention (rbias-by-delta from LDS) ----------------
__global__ __launch_bounds__(256, 2)
void attn_mfma_kernel(const unsigned short* __restrict__ qb,
                      const unsigned short* __restrict__ kb,
                      const unsigned short* __restrict__ vt,
                      const unsigned short* __restrict__ rbias,
                      const int* __restrict__ pmask,
                      unsigned short* __restrict__ att)
{
    __shared__ unsigned short Qs[64 * 64];
    __shared__ unsigned short Ks[128 * 64];
    __shared__ unsigned short Vt[64 * 128];
    __shared__ unsigned short Ps[4][16 * 128];
    __shared__ unsigned short rbs[2048];
    __shared__ unsigned short pmls[1024];

    const int tid = threadIdx.x;
    const int w = tid >> 6, lane = tid & 63;
    const int quad = lane >> 4, col = lane & 15;
    const int bp = blockIdx.y, i0 = blockIdx.x * 64;
    const int h = bp & 15, bb = bp >> 4;
    const size_t base = (size_t)bp << 16;
    const int myrow = w * 16;

    {
        const unsigned short* qg = qb + base + (size_t)i0 * 64;
        #pragma unroll
        for (int it = 0; it < 2; ++it) {
            int idx = it * 256 + tid;
            int r = idx >> 3, c = idx & 7;
            s8v d = *(const s8v*)(qg + (size_t)r * 64 + (c ^ (r & 7)) * 8);
            *(s8v*)(Qs + r * 64 + c * 8) = d;
        }
    }
    {
        const unsigned short* rg = rbias + h * 2048;
        #pragma unroll
        for (int it = 0; it < 8; ++it) rbs[it * 256 + tid] = rg[it * 256 + tid];
    }
    #pragma unroll
    for (int it = 0; it < 4; ++it) {
        int j = it * 256 + tid;
        pmls[j] = f2b(__logf((float)pmask[bb * 1024 + j]));
    }

    f32x4 O[4] = {};
    float mrow[4], lrow[4];
    #pragma unroll
    for (int r = 0; r < 4; ++r) { mrow[r] = -1e30f; lrow[r] = 0.f; }

    unsigned short* Pw = Ps[w];

    for (int jt = 0; jt < 8; ++jt) {
        const int j0 = jt * 128;
        __syncthreads();
        {
            const unsigned short* kg = kb + base + (size_t)j0 * 64;
            #pragma unroll
            for (int it = 0; it < 4; ++it) {
                int idx = it * 256 + tid;
                int r = idx >> 3, c = idx & 7;
                s8v d = *(const s8v*)(kg + (size_t)r * 64 + (c ^ (r & 7)) * 8);
                *(s8v*)(Ks + r * 64 + c * 8) = d;
            }
            const unsigned short* vg = vt + base + j0;
            #pragma unroll
            for (int it = 0; it < 4; ++it) {
                int idx = it * 256 + tid;
                int r = idx >> 4, c = idx & 15;
                s8v d = *(const s8v*)(vg + (size_t)r * 1024 + (c ^ (r & 15)) * 8);
                *(s8v*)(Vt + r * 128 + c * 8) = d;
            }
        }
        __syncthreads();

        f32x4 S[8] = {};
        #pragma unroll
        for (int ks = 0; ks < 2; ++ks) {
            int ar = myrow + col;
            s8v a = *(const s8v*)(Qs + ar * 64 + (((ks * 4 + quad) ^ (ar & 7)) * 8));
            #pragma unroll
            for (int ct = 0; ct < 8; ++ct) {
                int br = ct * 16 + col;
                s8v b = *(const s8v*)(Ks + br * 64 + (((ks * 4 + quad) ^ (br & 7)) * 8));
                S[ct] = __builtin_amdgcn_mfma_f32_16x16x32_bf16(a, b, S[ct], 0, 0, 0);
            }
        }

        float newm[4];
        #pragma unroll
        for (int r = 0; r < 4; ++r) newm[r] = mrow[r];
        #pragma unroll
        for (int ct = 0; ct < 8; ++ct) {
            int gj = j0 + ct * 16 + col;
            float pmv = bits2f(pmls[gj]);
            #pragma unroll
            for (int r = 0; r < 4; ++r) {
                int gr = i0 + myrow + quad * 4 + r;
                float s = S[ct][r] + bits2f(rbs[gj - gr + 1023]) + pmv;
                S[ct][r] = s;
                newm[r] = fmaxf(newm[r], s);
            }
        }
        #pragma unroll
        for (int off = 1; off < 16; off <<= 1)
            #pragma unroll
            for (int r = 0; r < 4; ++r)
                newm[r] = fmaxf(newm[r], __shfl_xor(newm[r], off));

        float alpha[4], lsum[4];
        #pragma unroll
        for (int r = 0; r < 4; ++r) { alpha[r] = __expf(mrow[r] - newm[r]); lsum[r] = 0.f; }
        #pragma unroll
        for (int ct = 0; ct < 8; ++ct)
            #pragma unroll
            for (int r = 0; r < 4; ++r) {
                float e = __expf(S[ct][r] - newm[r]);
                S[ct][r] = e;
                lsum[r] += e;
            }
        #pragma unroll
        for (int off = 1; off < 16; off <<= 1)
            #pragma unroll
            for (int r = 0; r < 4; ++r)
                lsum[r] += __shfl_xor(lsum[r], off);
        #pragma unroll
        for (int r = 0; r < 4; ++r) {
            lrow[r] = lrow[r] * alpha[r] + lsum[r];
            mrow[r] = newm[r];
        }
        #pragma unroll
        for (int nt = 0; nt < 4; ++nt)
            #pragma unroll
            for (int r = 0; r < 4; ++r)
                O[nt][r] *= alpha[r];

        #pragma unroll
        for (int ct = 0; ct < 8; ++ct)
            #pragma unroll
            for (int r = 0; r < 4; ++r) {
                int lr = quad * 4 + r;
                int j = ct * 16 + col;
                Pw[lr * 128 + (((j >> 3) ^ lr) << 3) + (j & 7)] = f2b(S[ct][r]);
            }

        #pragma unroll
        for (int kt = 0; kt < 4; ++kt) {
            int pr = col;
            s8v a = *(const s8v*)(Pw + pr * 128 + (((kt * 4 + quad) ^ pr) * 8));
            #pragma unroll
            for (int nt = 0; nt < 4; ++nt) {
                int vr = nt * 16 + col;
                s8v b = *(const s8v*)(Vt + vr * 128 + (((kt * 4 + quad) ^ (vr & 15)) * 8));
                O[nt] = __builtin_amdgcn_mfma_f32_16x16x32_bf16(a, b, O[nt], 0, 0, 0);
            }
        }
    }

    #pragma unroll
    for (int r = 0; r < 4; ++r) lrow[r] = 1.f / lrow[r];
    unsigned short* ag = att + base + (size_t)(i0 + myrow) * 64;
    #pragma unroll
    for (int nt = 0; nt < 4; ++nt)
        #pragma unroll
        for (int r = 0; r < 4; ++r)
            ag[(size_t)(quad * 4 + r) * 64 + nt * 16 + col] = f2b(O[nt][r] * lrow[r]);
}

// ---------------- layernorm over rows of 1024: in1+in2 -> (outF fp32, outB bf16) ----------------
template<typename TIN>
__global__ __launch_bounds__(256)
void ln_kernel(const TIN* __restrict__ in1, const TIN* __restrict__ in2,
               float* __restrict__ outF, unsigned short* __restrict__ outB)
{
    __shared__ float sred[8];
    const int row = blockIdx.x;
    const int tid = threadIdx.x;
    const size_t off = (size_t)row * 1024 + tid * 4;
    float a[4];
    load4(in1 + off, a);
    if (in2) {
        float b[4];
        load4(in2 + off, b);
        #pragma unroll
        for (int i = 0; i < 4; ++i) a[i] += b[i];
    }

    float lsum = a[0] + a[1] + a[2] + a[3];
    #pragma unroll
    for (int o = 32; o; o >>= 1) lsum += __shfl_down(lsum, o);
    const int lane = tid & 63, wid = tid >> 6;
    if (lane == 0) sred[wid] = lsum;
    __syncthreads();
    if (tid == 0) sred[4] = (sred[0] + sred[1] + sred[2] + sred[3]) * (1.f / 1024.f);
    __syncthreads();
    const float mean = sred[4];

    float d0 = a[0] - mean, d1 = a[1] - mean, d2 = a[2] - mean, d3 = a[3] - mean;
    float lsq = d0 * d0 + d1 * d1 + d2 * d2 + d3 * d3;
    #pragma unroll
    for (int o = 32; o; o >>= 1) lsq += __shfl_down(lsq, o);
    __syncthreads();
    if (lane == 0) sred[wid] = lsq;
    __syncthreads();
    if (tid == 0) sred[5] = rsqrtf((sred[0] + sred[1] + sred[2] + sred[3]) * (1.f / 1024.f));
    __syncthreads();
    const float r = sred[5];

    float o0 = d0 * r, o1 = d1 * r, o2 = d2 * r, o3 = d3 * r;
    if (outF) {
        float4 o = {o0, o1, o2, o3};
        *(float4*)&outF[off] = o;
    }
    if (outB) {
        ushort4 o = { f2b(o0), f2b(o1), f2b(o2), f2b(o3) };
        *(ushort4*)&outB[off] = o;
    }
}

extern "C" void kernel_launch(void* const* d_in, const int* in_sizes, int n_in,
                              void* d_out, int out_size, void* d_ws, size_t ws_size,
                              hipStream_t stream)
{
    const float* x     = (const float*)d_in[0];
    const int*   pmask = (const int*)  d_in[1];
    const float* Wq    = (const float*)d_in[2];
    const float* bq    = (const float*)d_in[3];
    const float* Wk    = (const float*)d_in[4];
    const float* bk    = (const float*)d_in[5];
    const float* Wv    = (const float*)d_in[6];
    const float* bv    = (const float*)d_in[7];
    const float* Wo    = (const float*)d_in[8];
    const float* bo    = (const float*)d_in[9];
    const float* rel   = (const float*)d_in[10];
    const float* W1    = (const float*)d_in[11];
    const float* b1    = (const float*)d_in[12];
    const float* W2    = (const float*)d_in[13];
    const float* b2    = (const float*)d_in[14];

    const int M = 4096, D = 1024;
    dim3 blk(256);

    // ---- workspace map (MB; peak write = 64MB+64KB, within round-5-proven envelope) ----
    char* ws = (char*)d_ws;
    unsigned short* W1b   = (unsigned short*)(ws);                 // 0-8    [read by ff1 gemm]
    unsigned short* W2b   = (unsigned short*)(ws + ( 8u << 20));   // 8-16   [read by ff2 gemm]
    unsigned short* xb    = (unsigned short*)(ws + (16u << 20));   // 16-24  [read by qkv gemm]
    unsigned short* Wqkvb = (unsigned short*)(ws + (24u << 20));   // 24-30  [read by qkv gemm]
    unsigned short* Wob   = (unsigned short*)(ws + (30u << 20));   // 30-32  [read by Wo gemm]
    unsigned short* qb    = (unsigned short*)(ws + (32u << 20));   // 32-40  [read by attn]
    unsigned short* kb    = (unsigned short*)(ws + (40u << 20));   // 40-48  [read by attn]
    unsigned short* vb    = (unsigned short*)(ws + (48u << 20));   // 48-56  [read by vtrans]
    unsigned short* vt    = (unsigned short*)(ws + (56u << 20));   // 56-64  [read by attn]
    unsigned short* rbias = (unsigned short*)(ws + (64u << 20));   // 64-64.0625 [read by attn]
    // phase-2 reuse (each region's previous tenant is dead before the write):
    float*          tmpA    = (float*)(ws + (32u << 20));          // 32-48  (qb/kb dead after attn)
    float*          tmpB    = (float*)(ws + (48u << 20));          // 48-64  (vb/vt dead after attn)
    unsigned short* attoutB = (unsigned short*)(ws + (16u << 20)); // 16-24  (xb dead after qkv gemm)
    unsigned short* ff1     = (unsigned short*)(ws + (32u << 20)); // 32-64  (tmpA/tmpB dead after ln1)
    unsigned short* ff2a    = (unsigned short*)(ws);               // 0-8    (W1b dead after ff1 gemm)
    unsigned short* ff2b    = (unsigned short*)(ws + (24u << 20)); // 24-32  (Wqkvb/Wob dead)
    unsigned short* attb    = (unsigned short*)d_out;              // d_out 0-8MB scratch (round-5-proven)

    // ---- conversions / tables ----
    cvt_kernel<<<4096, blk, 0, stream>>>(x,  xb, 1 << 20);
    cvt_kernel<<<1024, blk, 0, stream>>>(Wq, Wqkvb,              1 << 18);
    cvt_kernel<<<1024, blk, 0, stream>>>(Wk, Wqkvb + (1u << 20), 1 << 18);
    cvt_kernel<<<1024, blk, 0, stream>>>(Wv, Wqkvb + (2u << 20), 1 << 18);
    cvt_kernel<<<1024, blk, 0, stream>>>(Wo, Wob, 1 << 18);
    cvt_kernel<<<4096, blk, 0, stream>>>(W1, W1b, 1 << 20);
    cvt_kernel<<<4096, blk, 0, stream>>>(W2, W2b, 1 << 20);
    rbias_kernel<<<128, blk, 0, stream>>>(rel, rbias);

    // ---- fused QKV projection: N=3072, routed to qb/kb/vb ----
    mfma_gemm<unsigned short, float, 0, 1><<<dim3(24, 32), blk, 0, stream>>>(
        xb, D, Wqkvb, D, bq, bk, bv, (const float*)nullptr, qb, kb, vb, D, M, 3072, D);

    vtrans_kernel<<<4096, blk, 0, stream>>>(vb, vt);

    // ---- attention -> attb (d_out scratch, bf16) ----
    attn_mfma_kernel<<<dim3(16, 64), blk, 0, stream>>>(qb, kb, vt, rbias, pmask, attb);

    // ---- Wo projection + residual x, split-K z=2 -> tmpA/tmpB fp32; LN1 sums -> attoutB ----
    mfma_gemm<float, float, 0, 0><<<dim3(8, 32, 2), blk, 0, stream>>>(
        attb, D, Wob, D, bo, nullptr, nullptr, x, tmpA, tmpB, nullptr, D, M, D, 512);
    ln_kernel<float><<<4096, blk, 0, stream>>>(tmpA, tmpB, nullptr, attoutB);

    // ---- FFN: ff1 full N=4096; ff2 split-K z=2 (res = attoutB bf16) -> ff2a/ff2b; LN2 sums ----
    mfma_gemm<unsigned short, float, 1, 0><<<dim3(32, 32), blk, 0, stream>>>(
        attoutB, D, W1b, D, b1, nullptr, nullptr, (const float*)nullptr,
        ff1, nullptr, nullptr, 4096, M, 4096, D);
    mfma_gemm<unsigned short, unsigned short, 0, 0><<<dim3(8, 32, 2), blk, 0, stream>>>(
        ff1, 4096, W2b, 4096, b2, nullptr, nullptr, attoutB, ff2a, ff2b, nullptr, D, M, D, 2048);
    ln_kernel<unsigned short><<<4096, blk, 0, stream>>>(ff2a, ff2b, (float*)d_out, nullptr);
}

// Round 8
// 467.822 us; speedup vs baseline: 10.7809x; 1.0102x over previous
//
#include <hip/hip_runtime.h>
#include <hip/hip_bf16.h>

typedef __hip_bfloat16 bf16;
typedef __attribute__((ext_vector_type(8))) short s8v;      // 8 bf16 (4 VGPRs) MFMA A/B frag
typedef __attribute__((ext_vector_type(4))) float f32x4;    // MFMA C/D frag

__device__ __forceinline__ float bits2f(unsigned short u) {
    return __uint_as_float(((unsigned)u) << 16);
}
__device__ __forceinline__ unsigned short f2b(float f) {   // fp32 -> bf16 RNE
    union { float f; unsigned u; } x{f};
    return (unsigned short)((x.u + 0x7fff + ((x.u >> 16) & 1)) >> 16);
}
__device__ __forceinline__ float to_f(float x) { return x; }
__device__ __forceinline__ float to_f(unsigned short x) { return bits2f(x); }

__device__ __forceinline__ void load4(const float* p, float* a) {
    float4 t = *(const float4*)p;
    a[0] = t.x; a[1] = t.y; a[2] = t.z; a[3] = t.w;
}
__device__ __forceinline__ void load4(const unsigned short* p, float* a) {
    ushort4 t = *(const ushort4*)p;
    a[0] = bits2f(t.x); a[1] = bits2f(t.y); a[2] = bits2f(t.z); a[3] = bits2f(t.w);
}

// ---------------- fused fp32 -> bf16 convert of x + all weights ----------------
// i in float4 units: [0,1M) x ; [1M,2M) W1 ; [2M,3M) W2 ; [3M,4M) Wq|Wk|Wv|Wo (256K each)
__global__ __launch_bounds__(256)
void cvt_all_kernel(const float* __restrict__ x,
                    const float* __restrict__ Wq, const float* __restrict__ Wk,
                    const float* __restrict__ Wv, const float* __restrict__ Wo,
                    const float* __restrict__ W1, const float* __restrict__ W2,
                    unsigned short* __restrict__ xb, unsigned short* __restrict__ Wqkvb,
                    unsigned short* __restrict__ Wob,
                    unsigned short* __restrict__ W1b, unsigned short* __restrict__ W2b)
{
    int i = blockIdx.x * 256 + threadIdx.x;
    const float* src; unsigned short* dst; int off;
    if (i < (1 << 20))      { src = x;  dst = xb;  off = i; }
    else if (i < (2 << 20)) { src = W1; dst = W1b; off = i - (1 << 20); }
    else if (i < (3 << 20)) { src = W2; dst = W2b; off = i - (2 << 20); }
    else {
        int j = i - (3 << 20);
        int sel = j >> 18;
        off = j & ((1 << 18) - 1);
        src = sel == 0 ? Wq : sel == 1 ? Wk : sel == 2 ? Wv : Wo;
        dst = sel == 3 ? Wob : Wqkvb + ((size_t)sel << 20);
    }
    float4 v = ((const float4*)src)[off];
    ushort4 o = { f2b(v.x), f2b(v.y), f2b(v.z), f2b(v.w) };
    ((ushort4*)dst)[off] = o;
}

// ---------------- per-head relative-position bias by delta (T5 buckets, double math) ----------------
__global__ void rbias_kernel(const float* __restrict__ rel_emb, unsigned short* __restrict__ rbias)
{
    int idx = blockIdx.x * 256 + threadIdx.x;   // 16 * 2048
    if (idx >= 16 * 2048) return;
    int h = idx >> 11, q = idx & 2047;
    int n = q - 1023, ret = 0;                  // n = j - i
    if (n < 0) { ret = 16; n = -n; }
    int b;
    if (n < 8) b = n;
    else {
        double t = log((double)n / 8.0) / log(16.0) * 8.0;
        int v = 8 + (int)t;
        b = v < 15 ? v : 15;
    }
    rbias[idx] = f2b(rel_emb[(ret + b) * 16 + h]);
}

// ---------------- MFMA GEMM (proven round 7) ----------------
template<typename TC, typename TR, int RELU, int QKV>
__global__ __launch_bounds__(256)
void mfma_gemm(const unsigned short* __restrict__ A, int lda,
               const unsigned short* __restrict__ W, int ldw,
               const float* __restrict__ b0, const float* __restrict__ b1,
               const float* __restrict__ b2,
               const TR* __restrict__ res,
               void* __restrict__ C0, void* __restrict__ C1, void* __restrict__ C2,
               int ldc, int M, int N, int Ksplit)
{
    __shared__ unsigned short sm[2 * 128 * 32];
    unsigned short* As = sm;
    unsigned short* Ws = sm + 128 * 32;

    const int tid = threadIdx.x;
    const int w = tid >> 6, lane = tid & 63;
    const int quad = lane >> 4, col = lane & 15;
    const int m0 = blockIdx.y * 128, n0 = blockIdx.x * 128;
    const int wrow = (w & 1) * 64, wcol = (w >> 1) * 64;
    const int kz = blockIdx.z * Ksplit;

    const int srow   = lane >> 2;
    const int schunk = (lane & 3) ^ ((lane >> 4) & 3);

    f32x4 acc[4][4] = {};

    for (int k0 = kz; k0 < kz + Ksplit; k0 += 32) {
        __syncthreads();
        #pragma unroll
        for (int t = 0; t < 2; ++t) {
            const int rbase = w * 32 + t * 16;
            unsigned off = (unsigned)(rbase * 64);
            off = __builtin_amdgcn_readfirstlane(off);
            const unsigned short* ga = A + (size_t)(m0 + rbase + srow) * lda + k0 + schunk * 8;
            __builtin_amdgcn_global_load_lds(
                (const __attribute__((address_space(1))) unsigned int*)ga,
                (__attribute__((address_space(3))) unsigned int*)((char*)As + off), 16, 0, 0);
            const unsigned short* gw = W + (size_t)(n0 + rbase + srow) * ldw + k0 + schunk * 8;
            __builtin_amdgcn_global_load_lds(
                (const __attribute__((address_space(1))) unsigned int*)gw,
                (__attribute__((address_space(3))) unsigned int*)((char*)Ws + off), 16, 0, 0);
        }
        __syncthreads();

        s8v af[4], bfr[4];
        #pragma unroll
        for (int mt = 0; mt < 4; ++mt) {
            int rr = wrow + mt * 16 + col;
            af[mt] = *(const s8v*)(As + rr * 32 + ((quad ^ ((rr >> 2) & 3)) * 8));
        }
        #pragma unroll
        for (int nt = 0; nt < 4; ++nt) {
            int rr = wcol + nt * 16 + col;
            bfr[nt] = *(const s8v*)(Ws + rr * 32 + ((quad ^ ((rr >> 2) & 3)) * 8));
        }
        #pragma unroll
        for (int mt = 0; mt < 4; ++mt)
            #pragma unroll
            for (int nt = 0; nt < 4; ++nt)
                acc[mt][nt] = __builtin_amdgcn_mfma_f32_16x16x32_bf16(af[mt], bfr[nt], acc[mt][nt], 0, 0, 0);
    }

    if (QKV) {
        const int sel = n0 >> 10;
        unsigned short* Cb = (unsigned short*)(sel == 0 ? C0 : sel == 1 ? C1 : C2);
        const float* bs = sel == 0 ? b0 : sel == 1 ? b1 : b2;
        #pragma unroll
        for (int mt = 0; mt < 4; ++mt)
            #pragma unroll
            for (int rg = 0; rg < 4; ++rg) {
                int gm = m0 + wrow + mt * 16 + quad * 4 + rg;
                #pragma unroll
                for (int nt = 0; nt < 4; ++nt) {
                    int gnc = (n0 + wcol + nt * 16 + col) & 1023;
                    Cb[(size_t)gm * 1024 + gnc] = f2b(acc[mt][nt][rg] + bs[gnc]);
                }
            }
    } else {
        void* Cv = blockIdx.z ? C1 : C0;
        const bool z0 = (blockIdx.z == 0);
        #pragma unroll
        for (int mt = 0; mt < 4; ++mt)
            #pragma unroll
            for (int rg = 0; rg < 4; ++rg) {
                int gm = m0 + wrow + mt * 16 + quad * 4 + rg;
                #pragma unroll
                for (int nt = 0; nt < 4; ++nt) {
                    int gn = n0 + wcol + nt * 16 + col;
                    float c = acc[mt][nt][rg];
                    if (z0) {
                        if (b0)  c += b0[gn];
                        if (res) c += to_f(res[(size_t)gm * ldc + gn]);
                    }
                    if (RELU) c = fmaxf(c, 0.f);
                    if (sizeof(TC) == 2) ((unsigned short*)Cv)[(size_t)gm * ldc + gn] = f2b(c);
                    else                 ((float*)Cv)[(size_t)gm * ldc + gn] = c;
                }
            }
    }
}

// ---------------- V transpose: vb bf16 [4096][1024] -> vt bf16 [bp][d][j] ----------------
__global__ __launch_bounds__(256)
void vtrans_kernel(const unsigned short* __restrict__ v, unsigned short* __restrict__ vt)
{
    __shared__ unsigned short t[64][68];
    const int bpmm = blockIdx.x;
    const int bp = bpmm >> 6, mm = bpmm & 63;
    const unsigned short* vr = v + (size_t)(bp * 64 + mm) * 1024;
    const int tid = threadIdx.x;
    #pragma unroll
    for (int it = 0; it < 4; ++it) {
        int c = (tid >> 6) + it * 4;
        int d = tid & 63;
        t[d][c] = vr[c * 64 + d];
    }
    __syncthreads();
    int d = tid >> 2, qq = tid & 3;
    ushort4 o = { t[d][qq * 4 + 0], t[d][qq * 4 + 1], t[d][qq * 4 + 2], t[d][qq * 4 + 3] };
    *(ushort4*)(vt + (size_t)bp * 65536 + (size_t)d * 1024 + mm * 16 + qq * 4) = o;
}

// ---------------- MFMA attention v2: no max-subtraction, P aliased onto K tile ----------------
// grid (64, 16): bp = blockIdx.x (bp%8 -> stable XCD -> K/V L2-resident), i0 = blockIdx.y*64.
__global__ __launch_bounds__(256, 3)
void attn_mfma_kernel(const unsigned short* __restrict__ qb,
                      const unsigned short* __restrict__ kb,
                      const unsigned short* __restrict__ vt,
                      const unsigned short* __restrict__ rbias,
                      const int* __restrict__ pmask,
                      unsigned short* __restrict__ att)
{
    __shared__ unsigned short Qs[64 * 64];     // 8KB
    __shared__ unsigned short KP[128 * 64];    // 16KB: K tile, then per-wave P store
    __shared__ unsigned short Vt[64 * 128];    // 16KB
    __shared__ unsigned short rbs[2048];       // 4KB
    __shared__ unsigned short pmls[1024];      // 2KB

    const int tid = threadIdx.x;
    const int w = tid >> 6, lane = tid & 63;
    const int quad = lane >> 4, col = lane & 15;
    const int bp = blockIdx.x, i0 = blockIdx.y * 64;
    const int h = bp & 15, bb = bp >> 4;
    const size_t base = (size_t)bp << 16;
    const int myrow = w * 16;

    {
        const unsigned short* qg = qb + base + (size_t)i0 * 64;
        #pragma unroll
        for (int it = 0; it < 2; ++it) {
            int idx = it * 256 + tid;
            int r = idx >> 3, c = idx & 7;
            s8v d = *(const s8v*)(qg + (size_t)r * 64 + (c ^ (r & 7)) * 8);
            *(s8v*)(Qs + r * 64 + c * 8) = d;
        }
    }
    {
        const unsigned short* rg = rbias + h * 2048;
        #pragma unroll
        for (int it = 0; it < 8; ++it) rbs[it * 256 + tid] = rg[it * 256 + tid];
    }
    #pragma unroll
    for (int it = 0; it < 4; ++it) {
        int j = it * 256 + tid;
        pmls[j] = f2b(__logf((float)pmask[bb * 1024 + j]));
    }

    f32x4 O[4] = {};
    float lrow[4] = {0.f, 0.f, 0.f, 0.f};

    unsigned short* Pw = KP + w * 2048;   // 16 rows x 128 cols bf16

    for (int jt = 0; jt < 8; ++jt) {
        const int j0 = jt * 128;
        __syncthreads();   // prev iter's P/Vt readers done; Qs visible (jt=0)
        {
            const unsigned short* kg = kb + base + (size_t)j0 * 64;
            #pragma unroll
            for (int it = 0; it < 4; ++it) {
                int idx = it * 256 + tid;
                int r = idx >> 3, c = idx & 7;
                s8v d = *(const s8v*)(kg + (size_t)r * 64 + (c ^ (r & 7)) * 8);
                *(s8v*)(KP + r * 64 + c * 8) = d;
            }
            const unsigned short* vg = vt + base + j0;
            #pragma unroll
            for (int it = 0; it < 4; ++it) {
                int idx = it * 256 + tid;
                int r = idx >> 4, c = idx & 15;
                s8v d = *(const s8v*)(vg + (size_t)r * 1024 + (c ^ (r & 15)) * 8);
                *(s8v*)(Vt + r * 128 + c * 8) = d;
            }
        }
        __syncthreads();

        // S = Q @ K^T
        f32x4 S[8] = {};
        #pragma unroll
        for (int ks = 0; ks < 2; ++ks) {
            int ar = myrow + col;
            s8v a = *(const s8v*)(Qs + ar * 64 + (((ks * 4 + quad) ^ (ar & 7)) * 8));
            #pragma unroll
            for (int ct = 0; ct < 8; ++ct) {
                int br = ct * 16 + col;
                s8v b = *(const s8v*)(KP + br * 64 + (((ks * 4 + quad) ^ (br & 7)) * 8));
                S[ct] = __builtin_amdgcn_mfma_f32_16x16x32_bf16(a, b, S[ct], 0, 0, 0);
            }
        }

        // bias + exp + per-lane partial row-sum (no max subtraction: scores bounded)
        #pragma unroll
        for (int ct = 0; ct < 8; ++ct) {
            int gj = j0 + ct * 16 + col;
            float pmv = bits2f(pmls[gj]);
            int dbase = gj - (i0 + myrow + quad * 4) + 1023;
            #pragma unroll
            for (int r = 0; r < 4; ++r) {
                float e = __expf(S[ct][r] + bits2f(rbs[dbase - r]) + pmv);
                S[ct][r] = e;
                lrow[r] += e;
            }
        }

        __syncthreads();   // all waves done reading K rows from KP

        // write P (bf16) into own slice of KP
        #pragma unroll
        for (int ct = 0; ct < 8; ++ct)
            #pragma unroll
            for (int r = 0; r < 4; ++r) {
                int lr = quad * 4 + r;
                int j = ct * 16 + col;
                Pw[lr * 128 + (((j >> 3) ^ lr) << 3) + (j & 7)] = f2b(S[ct][r]);
            }

        // O += P @ V
        #pragma unroll
        for (int kt = 0; kt < 4; ++kt) {
            int pr = col;
            s8v a = *(const s8v*)(Pw + pr * 128 + (((kt * 4 + quad) ^ pr) * 8));
            #pragma unroll
            for (int nt = 0; nt < 4; ++nt) {
                int vr = nt * 16 + col;
                s8v b = *(const s8v*)(Vt + vr * 128 + (((kt * 4 + quad) ^ (vr & 15)) * 8));
                O[nt] = __builtin_amdgcn_mfma_f32_16x16x32_bf16(a, b, O[nt], 0, 0, 0);
            }
        }
    }

    // one final row-sum reduce across the 16 col-lanes, then normalize + store
    #pragma unroll
    for (int off = 1; off < 16; off <<= 1)
        #pragma unroll
        for (int r = 0; r < 4; ++r)
            lrow[r] += __shfl_xor(lrow[r], off);
    #pragma unroll
    for (int r = 0; r < 4; ++r) lrow[r] = 1.f / lrow[r];

    unsigned short* ag = att + base + (size_t)(i0 + myrow) * 64;
    #pragma unroll
    for (int nt = 0; nt < 4; ++nt)
        #pragma unroll
        for (int r = 0; r < 4; ++r)
            ag[(size_t)(quad * 4 + r) * 64 + nt * 16 + col] = f2b(O[nt][r] * lrow[r]);
}

// ---------------- layernorm over rows of 1024: in1+in2 -> (outF fp32, outB bf16) ----------------
template<typename TIN>
__global__ __launch_bounds__(256)
void ln_kernel(const TIN* __restrict__ in1, const TIN* __restrict__ in2,
               float* __restrict__ outF, unsigned short* __restrict__ outB)
{
    __shared__ float sred[8];
    const int row = blockIdx.x;
    const int tid = threadIdx.x;
    const size_t off = (size_t)row * 1024 + tid * 4;
    float a[4];
    load4(in1 + off, a);
    if (in2) {
        float b[4];
        load4(in2 + off, b);
        #pragma unroll
        for (int i = 0; i < 4; ++i) a[i] += b[i];
    }

    float lsum = a[0] + a[1] + a[2] + a[3];
    #pragma unroll
    for (int o = 32; o; o >>= 1) lsum += __shfl_down(lsum, o);
    const int lane = tid & 63, wid = tid >> 6;
    if (lane == 0) sred[wid] = lsum;
    __syncthreads();
    if (tid == 0) sred[4] = (sred[0] + sred[1] + sred[2] + sred[3]) * (1.f / 1024.f);
    __syncthreads();
    const float mean = sred[4];

    float d0 = a[0] - mean, d1 = a[1] - mean, d2 = a[2] - mean, d3 = a[3] - mean;
    float lsq = d0 * d0 + d1 * d1 + d2 * d2 + d3 * d3;
    #pragma unroll
    for (int o = 32; o; o >>= 1) lsq += __shfl_down(lsq, o);
    __syncthreads();
    if (lane == 0) sred[wid] = lsq;
    __syncthreads();
    if (tid == 0) sred[5] = rsqrtf((sred[0] + sred[1] + sred[2] + sred[3]) * (1.f / 1024.f));
    __syncthreads();
    const float r = sred[5];

    float o0 = d0 * r, o1 = d1 * r, o2 = d2 * r, o3 = d3 * r;
    if (outF) {
        float4 o = {o0, o1, o2, o3};
        *(float4*)&outF[off] = o;
    }
    if (outB) {
        ushort4 o = { f2b(o0), f2b(o1), f2b(o2), f2b(o3) };
        *(ushort4*)&outB[off] = o;
    }
}

extern "C" void kernel_launch(void* const* d_in, const int* in_sizes, int n_in,
                              void* d_out, int out_size, void* d_ws, size_t ws_size,
                              hipStream_t stream)
{
    const float* x     = (const float*)d_in[0];
    const int*   pmask = (const int*)  d_in[1];
    const float* Wq    = (const float*)d_in[2];
    const float* bq    = (const float*)d_in[3];
    const float* Wk    = (const float*)d_in[4];
    const float* bk    = (const float*)d_in[5];
    const float* Wv    = (const float*)d_in[6];
    const float* bv    = (const float*)d_in[7];
    const float* Wo    = (const float*)d_in[8];
    const float* bo    = (const float*)d_in[9];
    const float* rel   = (const float*)d_in[10];
    const float* W1    = (const float*)d_in[11];
    const float* b1    = (const float*)d_in[12];
    const float* W2    = (const float*)d_in[13];
    const float* b2    = (const float*)d_in[14];

    const int M = 4096, D = 1024;
    dim3 blk(256);

    // ---- workspace map (identical to round-7-proven; peak write 64MB+64KB) ----
    char* ws = (char*)d_ws;
    unsigned short* W1b   = (unsigned short*)(ws);                 // 0-8
    unsigned short* W2b   = (unsigned short*)(ws + ( 8u << 20));   // 8-16
    unsigned short* xb    = (unsigned short*)(ws + (16u << 20));   // 16-24
    unsigned short* Wqkvb = (unsigned short*)(ws + (24u << 20));   // 24-30
    unsigned short* Wob   = (unsigned short*)(ws + (30u << 20));   // 30-32
    unsigned short* qb    = (unsigned short*)(ws + (32u << 20));   // 32-40
    unsigned short* kb    = (unsigned short*)(ws + (40u << 20));   // 40-48
    unsigned short* vb    = (unsigned short*)(ws + (48u << 20));   // 48-56
    unsigned short* vt    = (unsigned short*)(ws + (56u << 20));   // 56-64
    unsigned short* rbias = (unsigned short*)(ws + (64u << 20));   // 64-64.0625
    float*          tmpA    = (float*)(ws + (32u << 20));          // 32-48 (qb/kb dead after attn)
    float*          tmpB    = (float*)(ws + (48u << 20));          // 48-64 (vb/vt dead after attn)
    unsigned short* attoutB = (unsigned short*)(ws + (16u << 20)); // 16-24 (xb dead after qkv)
    unsigned short* ff1     = (unsigned short*)(ws + (32u << 20)); // 32-64 (tmpA/B dead after ln1)
    unsigned short* ff2a    = (unsigned short*)(ws);               // 0-8   (W1b dead after ff1)
    unsigned short* ff2b    = (unsigned short*)(ws + (24u << 20)); // 24-32 (Wqkvb/Wob dead)
    unsigned short* attb    = (unsigned short*)d_out;              // d_out scratch (proven)

    // ---- conversions / tables ----
    cvt_all_kernel<<<16384, blk, 0, stream>>>(x, Wq, Wk, Wv, Wo, W1, W2,
                                              xb, Wqkvb, Wob, W1b, W2b);
    rbias_kernel<<<128, blk, 0, stream>>>(rel, rbias);

    // ---- fused QKV projection: N=3072, routed to qb/kb/vb ----
    mfma_gemm<unsigned short, float, 0, 1><<<dim3(24, 32), blk, 0, stream>>>(
        xb, D, Wqkvb, D, bq, bk, bv, (const float*)nullptr, qb, kb, vb, D, M, 3072, D);

    vtrans_kernel<<<4096, blk, 0, stream>>>(vb, vt);

    // ---- attention (bp-major grid for XCD L2 locality) ----
    attn_mfma_kernel<<<dim3(64, 16), blk, 0, stream>>>(qb, kb, vt, rbias, pmask, attb);

    // ---- Wo projection + residual x, split-K z=2 -> tmpA/tmpB fp32; LN1 -> attoutB ----
    mfma_gemm<float, float, 0, 0><<<dim3(8, 32, 2), blk, 0, stream>>>(
        attb, D, Wob, D, bo, nullptr, nullptr, x, tmpA, tmpB, nullptr, D, M, D, 512);
    ln_kernel<float><<<4096, blk, 0, stream>>>(tmpA, tmpB, nullptr, attoutB);

    // ---- FFN: ff1 full N=4096; ff2 split-K z=2 (res = attoutB bf16); LN2 sums ----
    mfma_gemm<unsigned short, float, 1, 0><<<dim3(32, 32), blk, 0, stream>>>(
        attoutB, D, W1b, D, b1, nullptr, nullptr, (const float*)nullptr,
        ff1, nullptr, nullptr, 4096, M, 4096, D);
    mfma_gemm<unsigned short, unsigned short, 0, 0><<<dim3(8, 32, 2), blk, 0, stream>>>(
        ff1, 4096, W2b, 4096, b2, nullptr, nullptr, attoutB, ff2a, ff2b, nullptr, D, M, D, 2048);
    ln_kernel<unsigned short><<<4096, blk, 0, stream>>>(ff2a, ff2b, (float*)d_out, nullptr);
}

// Round 9
// 438.856 us; speedup vs baseline: 11.4925x; 1.0660x over previous
//
#include <hip/hip_runtime.h>
#include <hip/hip_bf16.h>

typedef __hip_bfloat16 bf16;
typedef __attribute__((ext_vector_type(8))) short s8v;      // 8 bf16 (4 VGPRs) MFMA A/B frag
typedef __attribute__((ext_vector_type(4))) float f32x4;    // MFMA C/D frag

__device__ __forceinline__ float bits2f(unsigned short u) {
    return __uint_as_float(((unsigned)u) << 16);
}
__device__ __forceinline__ unsigned short f2b(float f) {   // fp32 -> bf16 RNE
    union { float f; unsigned u; } x{f};
    return (unsigned short)((x.u + 0x7fff + ((x.u >> 16) & 1)) >> 16);
}
__device__ __forceinline__ float to_f(float x) { return x; }
__device__ __forceinline__ float to_f(unsigned short x) { return bits2f(x); }

__device__ __forceinline__ void load4(const float* p, float* a) {
    float4 t = *(const float4*)p;
    a[0] = t.x; a[1] = t.y; a[2] = t.z; a[3] = t.w;
}
__device__ __forceinline__ void load4(const unsigned short* p, float* a) {
    ushort4 t = *(const ushort4*)p;
    a[0] = bits2f(t.x); a[1] = bits2f(t.y); a[2] = bits2f(t.z); a[3] = bits2f(t.w);
}

// ---------------- fused fp32 -> bf16 convert of x + all weights ----------------
__global__ __launch_bounds__(256)
void cvt_all_kernel(const float* __restrict__ x,
                    const float* __restrict__ Wq, const float* __restrict__ Wk,
                    const float* __restrict__ Wv, const float* __restrict__ Wo,
                    const float* __restrict__ W1, const float* __restrict__ W2,
                    unsigned short* __restrict__ xb, unsigned short* __restrict__ Wqkvb,
                    unsigned short* __restrict__ Wob,
                    unsigned short* __restrict__ W1b, unsigned short* __restrict__ W2b)
{
    int i = blockIdx.x * 256 + threadIdx.x;
    const float* src; unsigned short* dst; int off;
    if (i < (1 << 20))      { src = x;  dst = xb;  off = i; }
    else if (i < (2 << 20)) { src = W1; dst = W1b; off = i - (1 << 20); }
    else if (i < (3 << 20)) { src = W2; dst = W2b; off = i - (2 << 20); }
    else {
        int j = i - (3 << 20);
        int sel = j >> 18;
        off = j & ((1 << 18) - 1);
        src = sel == 0 ? Wq : sel == 1 ? Wk : sel == 2 ? Wv : Wo;
        dst = sel == 3 ? Wob : Wqkvb + ((size_t)sel << 20);
    }
    float4 v = ((const float4*)src)[off];
    ushort4 o = { f2b(v.x), f2b(v.y), f2b(v.z), f2b(v.w) };
    ((ushort4*)dst)[off] = o;
}

// ---------------- per-head relative-position bias by delta (T5 buckets, double math) ----------------
__global__ void rbias_kernel(const float* __restrict__ rel_emb, unsigned short* __restrict__ rbias)
{
    int idx = blockIdx.x * 256 + threadIdx.x;   // 16 * 2048
    if (idx >= 16 * 2048) return;
    int h = idx >> 11, q = idx & 2047;
    int n = q - 1023, ret = 0;                  // n = j - i
    if (n < 0) { ret = 16; n = -n; }
    int b;
    if (n < 8) b = n;
    else {
        double t = log((double)n / 8.0) / log(16.0) * 8.0;
        int v = 8 + (int)t;
        b = v < 15 ? v : 15;
    }
    rbias[idx] = f2b(rel_emb[(ret + b) * 16 + h]);
}

// ---------------- MFMA GEMM (proven round 7/8) ----------------
template<typename TC, typename TR, int RELU, int QKV>
__global__ __launch_bounds__(256)
void mfma_gemm(const unsigned short* __restrict__ A, int lda,
               const unsigned short* __restrict__ W, int ldw,
               const float* __restrict__ b0, const float* __restrict__ b1,
               const float* __restrict__ b2,
               const TR* __restrict__ res,
               void* __restrict__ C0, void* __restrict__ C1, void* __restrict__ C2,
               int ldc, int M, int N, int Ksplit)
{
    __shared__ unsigned short sm[2 * 128 * 32];
    unsigned short* As = sm;
    unsigned short* Ws = sm + 128 * 32;

    const int tid = threadIdx.x;
    const int w = tid >> 6, lane = tid & 63;
    const int quad = lane >> 4, col = lane & 15;
    const int m0 = blockIdx.y * 128, n0 = blockIdx.x * 128;
    const int wrow = (w & 1) * 64, wcol = (w >> 1) * 64;
    const int kz = blockIdx.z * Ksplit;

    const int srow   = lane >> 2;
    const int schunk = (lane & 3) ^ ((lane >> 4) & 3);

    f32x4 acc[4][4] = {};

    for (int k0 = kz; k0 < kz + Ksplit; k0 += 32) {
        __syncthreads();
        #pragma unroll
        for (int t = 0; t < 2; ++t) {
            const int rbase = w * 32 + t * 16;
            unsigned off = (unsigned)(rbase * 64);
            off = __builtin_amdgcn_readfirstlane(off);
            const unsigned short* ga = A + (size_t)(m0 + rbase + srow) * lda + k0 + schunk * 8;
            __builtin_amdgcn_global_load_lds(
                (const __attribute__((address_space(1))) unsigned int*)ga,
                (__attribute__((address_space(3))) unsigned int*)((char*)As + off), 16, 0, 0);
            const unsigned short* gw = W + (size_t)(n0 + rbase + srow) * ldw + k0 + schunk * 8;
            __builtin_amdgcn_global_load_lds(
                (const __attribute__((address_space(1))) unsigned int*)gw,
                (__attribute__((address_space(3))) unsigned int*)((char*)Ws + off), 16, 0, 0);
        }
        __syncthreads();

        s8v af[4], bfr[4];
        #pragma unroll
        for (int mt = 0; mt < 4; ++mt) {
            int rr = wrow + mt * 16 + col;
            af[mt] = *(const s8v*)(As + rr * 32 + ((quad ^ ((rr >> 2) & 3)) * 8));
        }
        #pragma unroll
        for (int nt = 0; nt < 4; ++nt) {
            int rr = wcol + nt * 16 + col;
            bfr[nt] = *(const s8v*)(Ws + rr * 32 + ((quad ^ ((rr >> 2) & 3)) * 8));
        }
        #pragma unroll
        for (int mt = 0; mt < 4; ++mt)
            #pragma unroll
            for (int nt = 0; nt < 4; ++nt)
                acc[mt][nt] = __builtin_amdgcn_mfma_f32_16x16x32_bf16(af[mt], bfr[nt], acc[mt][nt], 0, 0, 0);
    }

    if (QKV) {
        const int sel = n0 >> 10;
        unsigned short* Cb = (unsigned short*)(sel == 0 ? C0 : sel == 1 ? C1 : C2);
        const float* bs = sel == 0 ? b0 : sel == 1 ? b1 : b2;
        #pragma unroll
        for (int mt = 0; mt < 4; ++mt)
            #pragma unroll
            for (int rg = 0; rg < 4; ++rg) {
                int gm = m0 + wrow + mt * 16 + quad * 4 + rg;
                #pragma unroll
                for (int nt = 0; nt < 4; ++nt) {
                    int gnc = (n0 + wcol + nt * 16 + col) & 1023;
                    Cb[(size_t)gm * 1024 + gnc] = f2b(acc[mt][nt][rg] + bs[gnc]);
                }
            }
    } else {
        void* Cv = blockIdx.z ? C1 : C0;
        const bool z0 = (blockIdx.z == 0);
        #pragma unroll
        for (int mt = 0; mt < 4; ++mt)
            #pragma unroll
            for (int rg = 0; rg < 4; ++rg) {
                int gm = m0 + wrow + mt * 16 + quad * 4 + rg;
                #pragma unroll
                for (int nt = 0; nt < 4; ++nt) {
                    int gn = n0 + wcol + nt * 16 + col;
                    float c = acc[mt][nt][rg];
                    if (z0) {
                        if (b0)  c += b0[gn];
                        if (res) c += to_f(res[(size_t)gm * ldc + gn]);
                    }
                    if (RELU) c = fmaxf(c, 0.f);
                    if (sizeof(TC) == 2) ((unsigned short*)Cv)[(size_t)gm * ldc + gn] = f2b(c);
                    else                 ((float*)Cv)[(size_t)gm * ldc + gn] = c;
                }
            }
    }
}

// ---------------- V transpose: vb bf16 [4096][1024] -> vt bf16 [bp][d][j] ----------------
__global__ __launch_bounds__(256)
void vtrans_kernel(const unsigned short* __restrict__ v, unsigned short* __restrict__ vt)
{
    __shared__ unsigned short t[64][68];
    const int bpmm = blockIdx.x;
    const int bp = bpmm >> 6, mm = bpmm & 63;
    const unsigned short* vr = v + (size_t)(bp * 64 + mm) * 1024;
    const int tid = threadIdx.x;
    #pragma unroll
    for (int it = 0; it < 4; ++it) {
        int c = (tid >> 6) + it * 4;
        int d = tid & 63;
        t[d][c] = vr[c * 64 + d];
    }
    __syncthreads();
    int d = tid >> 2, qq = tid & 3;
    ushort4 o = { t[d][qq * 4 + 0], t[d][qq * 4 + 1], t[d][qq * 4 + 2], t[d][qq * 4 + 3] };
    *(ushort4*)(vt + (size_t)bp * 65536 + (size_t)d * 1024 + mm * 16 + qq * 4) = o;
}

// ---------------- MFMA attention v3: 128-query tiles, 2 blocks/CU even ----------------
// grid (64, 8): bp = blockIdx.x (bp%8 -> stable XCD, K/V L2-resident), i0 = blockIdx.y*128.
// Each wave owns 32 query rows (2 row-tiles). No max-subtraction (scores bounded).
// P round-trips twice through the per-wave 16-row LDS slice (within-wave ordering, no barrier).
__global__ __launch_bounds__(256, 2)
void attn_mfma_kernel(const unsigned short* __restrict__ qb,
                      const unsigned short* __restrict__ kb,
                      const unsigned short* __restrict__ vt,
                      const unsigned short* __restrict__ rbias,
                      const int* __restrict__ pmask,
                      unsigned short* __restrict__ att)
{
    __shared__ unsigned short Qs[128 * 64];    // 16KB
    __shared__ unsigned short KP[128 * 64];    // 16KB: K tile, then per-wave P slices
    __shared__ unsigned short Vt[64 * 128];    // 16KB
    __shared__ unsigned short rbs[2048];       // 4KB
    __shared__ unsigned short pmls[1024];      // 2KB

    const int tid = threadIdx.x;
    const int w = tid >> 6, lane = tid & 63;
    const int quad = lane >> 4, col = lane & 15;
    const int bp = blockIdx.x, i0 = blockIdx.y * 128;
    const int h = bp & 15, bb = bp >> 4;
    const size_t base = (size_t)bp << 16;
    const int myrow0 = w * 32, myrow1 = w * 32 + 16;

    {   // stage Q: 128 rows x 8 chunks
        const unsigned short* qg = qb + base + (size_t)i0 * 64;
        #pragma unroll
        for (int it = 0; it < 4; ++it) {
            int idx = it * 256 + tid;
            int r = idx >> 3, c = idx & 7;
            s8v d = *(const s8v*)(qg + (size_t)r * 64 + (c ^ (r & 7)) * 8);
            *(s8v*)(Qs + r * 64 + c * 8) = d;
        }
    }
    {
        const unsigned short* rg = rbias + h * 2048;
        #pragma unroll
        for (int it = 0; it < 8; ++it) rbs[it * 256 + tid] = rg[it * 256 + tid];
    }
    #pragma unroll
    for (int it = 0; it < 4; ++it) {
        int j = it * 256 + tid;
        pmls[j] = f2b(__logf((float)pmask[bb * 1024 + j]));
    }

    f32x4 O0[4] = {}, O1[4] = {};
    float lrow0[4] = {0.f, 0.f, 0.f, 0.f};
    float lrow1[4] = {0.f, 0.f, 0.f, 0.f};

    unsigned short* Pw = KP + w * 2048;   // per-wave 16 rows x 128 cols

    for (int jt = 0; jt < 8; ++jt) {
        const int j0 = jt * 128;
        __syncthreads();   // prev iter's P/Vt readers done; Qs visible (jt=0)
        {
            const unsigned short* kg = kb + base + (size_t)j0 * 64;
            #pragma unroll
            for (int it = 0; it < 4; ++it) {
                int idx = it * 256 + tid;
                int r = idx >> 3, c = idx & 7;
                s8v d = *(const s8v*)(kg + (size_t)r * 64 + (c ^ (r & 7)) * 8);
                *(s8v*)(KP + r * 64 + c * 8) = d;
            }
            const unsigned short* vg = vt + base + j0;
            #pragma unroll
            for (int it = 0; it < 4; ++it) {
                int idx = it * 256 + tid;
                int r = idx >> 4, c = idx & 15;
                s8v d = *(const s8v*)(vg + (size_t)r * 1024 + (c ^ (r & 15)) * 8);
                *(s8v*)(Vt + r * 128 + c * 8) = d;
            }
        }
        __syncthreads();

        // S = Q @ K^T for both row-tiles (B-frag reused across the two)
        f32x4 S0[8] = {}, S1[8] = {};
        #pragma unroll
        for (int ks = 0; ks < 2; ++ks) {
            int ar0 = myrow0 + col, ar1 = myrow1 + col;
            s8v a0 = *(const s8v*)(Qs + ar0 * 64 + (((ks * 4 + quad) ^ (ar0 & 7)) * 8));
            s8v a1 = *(const s8v*)(Qs + ar1 * 64 + (((ks * 4 + quad) ^ (ar1 & 7)) * 8));
            #pragma unroll
            for (int ct = 0; ct < 8; ++ct) {
                int br = ct * 16 + col;
                s8v b = *(const s8v*)(KP + br * 64 + (((ks * 4 + quad) ^ (br & 7)) * 8));
                S0[ct] = __builtin_amdgcn_mfma_f32_16x16x32_bf16(a0, b, S0[ct], 0, 0, 0);
                S1[ct] = __builtin_amdgcn_mfma_f32_16x16x32_bf16(a1, b, S1[ct], 0, 0, 0);
            }
        }

        // bias + exp + partial row-sums (no max subtraction)
        #pragma unroll
        for (int ct = 0; ct < 8; ++ct) {
            int gj = j0 + ct * 16 + col;
            float pmv = bits2f(pmls[gj]);
            int d0 = gj - (i0 + myrow0 + quad * 4) + 1023;
            int d1 = gj - (i0 + myrow1 + quad * 4) + 1023;
            #pragma unroll
            for (int r = 0; r < 4; ++r) {
                float e0 = __expf(S0[ct][r] + bits2f(rbs[d0 - r]) + pmv);
                float e1 = __expf(S1[ct][r] + bits2f(rbs[d1 - r]) + pmv);
                S0[ct][r] = e0; lrow0[r] += e0;
                S1[ct][r] = e1; lrow1[r] += e1;
            }
        }

        __syncthreads();   // all waves done reading K rows from KP

        // tile0: write P0 into own slice, then O0 += P0 @ V
        #pragma unroll
        for (int ct = 0; ct < 8; ++ct)
            #pragma unroll
            for (int r = 0; r < 4; ++r) {
                int lr = quad * 4 + r;
                int j = ct * 16 + col;
                Pw[lr * 128 + (((j >> 3) ^ lr) << 3) + (j & 7)] = f2b(S0[ct][r]);
            }
        #pragma unroll
        for (int kt = 0; kt < 4; ++kt) {
            int pr = col;
            s8v a = *(const s8v*)(Pw + pr * 128 + (((kt * 4 + quad) ^ pr) * 8));
            #pragma unroll
            for (int nt = 0; nt < 4; ++nt) {
                int vr = nt * 16 + col;
                s8v b = *(const s8v*)(Vt + vr * 128 + (((kt * 4 + quad) ^ (vr & 15)) * 8));
                O0[nt] = __builtin_amdgcn_mfma_f32_16x16x32_bf16(a, b, O0[nt], 0, 0, 0);
            }
        }

        // tile1: overwrite same slice (within-wave LDS ordering), then O1 += P1 @ V
        #pragma unroll
        for (int ct = 0; ct < 8; ++ct)
            #pragma unroll
            for (int r = 0; r < 4; ++r) {
                int lr = quad * 4 + r;
                int j = ct * 16 + col;
                Pw[lr * 128 + (((j >> 3) ^ lr) << 3) + (j & 7)] = f2b(S1[ct][r]);
            }
        #pragma unroll
        for (int kt = 0; kt < 4; ++kt) {
            int pr = col;
            s8v a = *(const s8v*)(Pw + pr * 128 + (((kt * 4 + quad) ^ pr) * 8));
            #pragma unroll
            for (int nt = 0; nt < 4; ++nt) {
                int vr = nt * 16 + col;
                s8v b = *(const s8v*)(Vt + vr * 128 + (((kt * 4 + quad) ^ (vr & 15)) * 8));
                O1[nt] = __builtin_amdgcn_mfma_f32_16x16x32_bf16(a, b, O1[nt], 0, 0, 0);
            }
        }
    }

    // final row-sum reduce across 16 col-lanes, normalize, store
    #pragma unroll
    for (int off = 1; off < 16; off <<= 1)
        #pragma unroll
        for (int r = 0; r < 4; ++r) {
            lrow0[r] += __shfl_xor(lrow0[r], off);
            lrow1[r] += __shfl_xor(lrow1[r], off);
        }
    #pragma unroll
    for (int r = 0; r < 4; ++r) {
        lrow0[r] = 1.f / lrow0[r];
        lrow1[r] = 1.f / lrow1[r];
    }

    unsigned short* ag0 = att + base + (size_t)(i0 + myrow0) * 64;
    unsigned short* ag1 = att + base + (size_t)(i0 + myrow1) * 64;
    #pragma unroll
    for (int nt = 0; nt < 4; ++nt)
        #pragma unroll
        for (int r = 0; r < 4; ++r) {
            ag0[(size_t)(quad * 4 + r) * 64 + nt * 16 + col] = f2b(O0[nt][r] * lrow0[r]);
            ag1[(size_t)(quad * 4 + r) * 64 + nt * 16 + col] = f2b(O1[nt][r] * lrow1[r]);
        }
}

// ---------------- layernorm over rows of 1024: in1+in2 -> (outF fp32, outB bf16) ----------------
template<typename TIN>
__global__ __launch_bounds__(256)
void ln_kernel(const TIN* __restrict__ in1, const TIN* __restrict__ in2,
               float* __restrict__ outF, unsigned short* __restrict__ outB)
{
    __shared__ float sred[8];
    const int row = blockIdx.x;
    const int tid = threadIdx.x;
    const size_t off = (size_t)row * 1024 + tid * 4;
    float a[4];
    load4(in1 + off, a);
    if (in2) {
        float b[4];
        load4(in2 + off, b);
        #pragma unroll
        for (int i = 0; i < 4; ++i) a[i] += b[i];
    }

    float lsum = a[0] + a[1] + a[2] + a[3];
    #pragma unroll
    for (int o = 32; o; o >>= 1) lsum += __shfl_down(lsum, o);
    const int lane = tid & 63, wid = tid >> 6;
    if (lane == 0) sred[wid] = lsum;
    __syncthreads();
    if (tid == 0) sred[4] = (sred[0] + sred[1] + sred[2] + sred[3]) * (1.f / 1024.f);
    __syncthreads();
    const float mean = sred[4];

    float d0 = a[0] - mean, d1 = a[1] - mean, d2 = a[2] - mean, d3 = a[3] - mean;
    float lsq = d0 * d0 + d1 * d1 + d2 * d2 + d3 * d3;
    #pragma unroll
    for (int o = 32; o; o >>= 1) lsq += __shfl_down(lsq, o);
    __syncthreads();
    if (lane == 0) sred[wid] = lsq;
    __syncthreads();
    if (tid == 0) sred[5] = rsqrtf((sred[0] + sred[1] + sred[2] + sred[3]) * (1.f / 1024.f));
    __syncthreads();
    const float r = sred[5];

    float o0 = d0 * r, o1 = d1 * r, o2 = d2 * r, o3 = d3 * r;
    if (outF) {
        float4 o = {o0, o1, o2, o3};
        *(float4*)&outF[off] = o;
    }
    if (outB) {
        ushort4 o = { f2b(o0), f2b(o1), f2b(o2), f2b(o3) };
        *(ushort4*)&outB[off] = o;
    }
}

extern "C" void kernel_launch(void* const* d_in, const int* in_sizes, int n_in,
                              void* d_out, int out_size, void* d_ws, size_t ws_size,
                              hipStream_t stream)
{
    const float* x     = (const float*)d_in[0];
    const int*   pmask = (const int*)  d_in[1];
    const float* Wq    = (const float*)d_in[2];
    const float* bq    = (const float*)d_in[3];
    const float* Wk    = (const float*)d_in[4];
    const float* bk    = (const float*)d_in[5];
    const float* Wv    = (const float*)d_in[6];
    const float* bv    = (const float*)d_in[7];
    const float* Wo    = (const float*)d_in[8];
    const float* bo    = (const float*)d_in[9];
    const float* rel   = (const float*)d_in[10];
    const float* W1    = (const float*)d_in[11];
    const float* b1    = (const float*)d_in[12];
    const float* W2    = (const float*)d_in[13];
    const float* b2    = (const float*)d_in[14];

    const int M = 4096, D = 1024;
    dim3 blk(256);

    // ---- workspace map (identical to round-7/8-proven; peak write 64MB+64KB) ----
    char* ws = (char*)d_ws;
    unsigned short* W1b   = (unsigned short*)(ws);                 // 0-8
    unsigned short* W2b   = (unsigned short*)(ws + ( 8u << 20));   // 8-16
    unsigned short* xb    = (unsigned short*)(ws + (16u << 20));   // 16-24
    unsigned short* Wqkvb = (unsigned short*)(ws + (24u << 20));   // 24-30
    unsigned short* Wob   = (unsigned short*)(ws + (30u << 20));   // 30-32
    unsigned short* qb    = (unsigned short*)(ws + (32u << 20));   // 32-40
    unsigned short* kb    = (unsigned short*)(ws + (40u << 20));   // 40-48
    unsigned short* vb    = (unsigned short*)(ws + (48u << 20));   // 48-56
    unsigned short* vt    = (unsigned short*)(ws + (56u << 20));   // 56-64
    unsigned short* rbias = (unsigned short*)(ws + (64u << 20));   // 64-64.0625
    float*          tmpA    = (float*)(ws + (32u << 20));          // 32-48 (qb/kb dead after attn)
    float*          tmpB    = (float*)(ws + (48u << 20));          // 48-64 (vb/vt dead after attn)
    unsigned short* attoutB = (unsigned short*)(ws + (16u << 20)); // 16-24 (xb dead after qkv)
    unsigned short* ff1     = (unsigned short*)(ws + (32u << 20)); // 32-64 (tmpA/B dead after ln1)
    unsigned short* ff2a    = (unsigned short*)(ws);               // 0-8   (W1b dead after ff1)
    unsigned short* ff2b    = (unsigned short*)(ws + (24u << 20)); // 24-32 (Wqkvb/Wob dead)
    unsigned short* attb    = (unsigned short*)d_out;              // d_out scratch (proven)

    // ---- conversions / tables ----
    cvt_all_kernel<<<16384, blk, 0, stream>>>(x, Wq, Wk, Wv, Wo, W1, W2,
                                              xb, Wqkvb, Wob, W1b, W2b);
    rbias_kernel<<<128, blk, 0, stream>>>(rel, rbias);

    // ---- fused QKV projection: N=3072, routed to qb/kb/vb ----
    mfma_gemm<unsigned short, float, 0, 1><<<dim3(24, 32), blk, 0, stream>>>(
        xb, D, Wqkvb, D, bq, bk, bv, (const float*)nullptr, qb, kb, vb, D, M, 3072, D);

    vtrans_kernel<<<4096, blk, 0, stream>>>(vb, vt);

    // ---- attention v3: 128-query tiles, bp-major grid, 2 blocks/CU even ----
    attn_mfma_kernel<<<dim3(64, 8), blk, 0, stream>>>(qb, kb, vt, rbias, pmask, attb);

    // ---- Wo projection + residual x, split-K z=2 -> tmpA/tmpB fp32; LN1 -> attoutB ----
    mfma_gemm<float, float, 0, 0><<<dim3(8, 32, 2), blk, 0, stream>>>(
        attb, D, Wob, D, bo, nullptr, nullptr, x, tmpA, tmpB, nullptr, D, M, D, 512);
    ln_kernel<float><<<4096, blk, 0, stream>>>(tmpA, tmpB, nullptr, attoutB);

    // ---- FFN: ff1 full N=4096; ff2 split-K z=2 (res = attoutB bf16); LN2 sums ----
    mfma_gemm<unsigned short, float, 1, 0><<<dim3(32, 32), blk, 0, stream>>>(
        attoutB, D, W1b, D, b1, nullptr, nullptr, (const float*)nullptr,
        ff1, nullptr, nullptr, 4096, M, 4096, D);
    mfma_gemm<unsigned short, unsigned short, 0, 0><<<dim3(8, 32, 2), blk, 0, stream>>>(
        ff1, 4096, W2b, 4096, b2, nullptr, nullptr, attoutB, ff2a, ff2b, nullptr, D, M, D, 2048);
    ln_kernel<unsigned short><<<4096, blk, 0, stream>>>(ff2a, ff2b, (float*)d_out, nullptr);
}